// Round 1
// baseline (1177.840 us; speedup 1.0000x reference)
//
#include <hip/hip_runtime.h>
#include <math.h>

#define DIN 512
#define HID 128
#define DOUT 20

typedef unsigned int u32;

// ordered-uint encoding for float atomicMax (valid for all non-NaN floats)
__device__ __forceinline__ u32 encf(float f) {
  u32 u = __float_as_uint(f);
  return (u & 0x80000000u) ? ~u : (u | 0x80000000u);
}
__device__ __forceinline__ float decf(u32 u) {
  u32 b = (u & 0x80000000u) ? (u ^ 0x80000000u) : ~u;
  return __uint_as_float(b);
}

// ---------- prep: vr1 = W1r^T @ a1r  (512), vr2 = W2r^T @ a2r (128) ----------
__global__ void k_prep(const float* __restrict__ W1r, const float* __restrict__ a1r,
                       const float* __restrict__ W2r, const float* __restrict__ a2r,
                       float* __restrict__ vr1, float* __restrict__ vr2) {
  int t = threadIdx.x;
  for (int k = t; k < DIN; k += 256) {
    float s = 0.f;
    for (int c = 0; c < HID; ++c) s = fmaf(a1r[c], W1r[c * DIN + k], s);
    vr1[k] = s;
  }
  if (t < HID) {
    float s = 0.f;
    for (int c = 0; c < DOUT; ++c) s = fmaf(a2r[c], W2r[c * HID + t], s);
    vr2[t] = s;
  }
}

// ---------- init segment-max buffers to enc(-inf) = 0x007FFFFF ----------
__global__ void k_fill(u32* __restrict__ emax1, u32* __restrict__ emax2,
                       u32* __restrict__ colmaxU, int n) {
  int stride = gridDim.x * blockDim.x;
  for (int i = blockIdx.x * blockDim.x + threadIdx.x; i < n; i += stride) {
    emax1[i] = 0x007FFFFFu;
    emax2[i] = 0x007FFFFFu;
  }
  if (blockIdx.x == 0 && threadIdx.x < 32) colmaxU[threadIdx.x] = 0x007FFFFFu;
}

// ---------- GEMM: xl1 = x @ W1l^T  [M,128], epilogue el1 = xl1 @ a1l ----------
__launch_bounds__(256)
__global__ void k_gemm1(const float* __restrict__ x, const float* __restrict__ W,
                        const float* __restrict__ al, float* __restrict__ xl1,
                        float* __restrict__ el1, int M) {
  __shared__ float xs[64][33];    // 64 rows x 32 k (+1 pad)
  __shared__ float ws[32][132];   // 32 k x 128 cols (+4 pad, keeps rows 16B-aligned)
  const int tid = threadIdx.x;
  const int tx = tid & 15;        // col group: cols tx*8 .. tx*8+7
  const int ty = tid >> 4;        // row group: rows ty*4 .. ty*4+3
  const int brow = blockIdx.x * 64;
  float acc[4][8] = {};
  for (int k0 = 0; k0 < DIN; k0 += 32) {
#pragma unroll
    for (int i = 0; i < 2; ++i) {          // x tile: 512 float4 slots
      int s = tid * 2 + i;
      int r = s >> 3, k4 = s & 7;
      float4 v = make_float4(0.f, 0.f, 0.f, 0.f);
      int grow = brow + r;
      if (grow < M) v = *(const float4*)(x + (size_t)grow * DIN + k0 + k4 * 4);
      xs[r][k4 * 4 + 0] = v.x; xs[r][k4 * 4 + 1] = v.y;
      xs[r][k4 * 4 + 2] = v.z; xs[r][k4 * 4 + 3] = v.w;
    }
#pragma unroll
    for (int i = 0; i < 4; ++i) {          // W tile: 1024 float4 slots, transposed
      int s = tid * 4 + i;
      int c = s >> 3, k4 = s & 7;
      float4 v = *(const float4*)(W + (size_t)c * DIN + k0 + k4 * 4);
      ws[k4 * 4 + 0][c] = v.x; ws[k4 * 4 + 1][c] = v.y;
      ws[k4 * 4 + 2][c] = v.z; ws[k4 * 4 + 3][c] = v.w;
    }
    __syncthreads();
#pragma unroll
    for (int kk = 0; kk < 32; ++kk) {
      float xv[4];
#pragma unroll
      for (int r = 0; r < 4; ++r) xv[r] = xs[ty * 4 + r][kk];
      float4 w0 = *(const float4*)&ws[kk][tx * 8];
      float4 w1 = *(const float4*)&ws[kk][tx * 8 + 4];
      float wv[8] = {w0.x, w0.y, w0.z, w0.w, w1.x, w1.y, w1.z, w1.w};
#pragma unroll
      for (int r = 0; r < 4; ++r)
#pragma unroll
        for (int c = 0; c < 8; ++c)
          acc[r][c] = fmaf(xv[r], wv[c], acc[r][c]);
    }
    __syncthreads();
  }
  float alv[8];
#pragma unroll
  for (int c = 0; c < 8; ++c) alv[c] = al[tx * 8 + c];
#pragma unroll
  for (int r = 0; r < 4; ++r) {
    int grow = brow + ty * 4 + r;
    float part = 0.f;
#pragma unroll
    for (int c = 0; c < 8; ++c) part = fmaf(acc[r][c], alv[c], part);
    part += __shfl_xor(part, 1);
    part += __shfl_xor(part, 2);
    part += __shfl_xor(part, 4);
    part += __shfl_xor(part, 8);   // reduce over the 16 tx lanes
    if (grow < M) {
      *(float4*)(xl1 + (size_t)grow * HID + tx * 8) =
          make_float4(acc[r][0], acc[r][1], acc[r][2], acc[r][3]);
      *(float4*)(xl1 + (size_t)grow * HID + tx * 8 + 4) =
          make_float4(acc[r][4], acc[r][5], acc[r][6], acc[r][7]);
      if (tx == 0) el1[grow] = part;
    }
  }
}

// ---------- per-node: ms0 = x@W0^T + b0, er1 = x@vr1 (32 lanes per node) ----------
__launch_bounds__(256)
__global__ void k_node1(const float* __restrict__ x, const float* __restrict__ W0,
                        const float* __restrict__ b0, const float* __restrict__ vr1,
                        float* __restrict__ ms0, float* __restrict__ er1, int M) {
  int g = threadIdx.x >> 5, lane = threadIdx.x & 31;
  int node = blockIdx.x * 8 + g;
  if (node >= M) return;
  float xv[16];
#pragma unroll
  for (int j4 = 0; j4 < 4; ++j4) {
    float4 v = *(const float4*)(x + (size_t)node * DIN + (lane + j4 * 32) * 4);
    xv[j4 * 4 + 0] = v.x; xv[j4 * 4 + 1] = v.y;
    xv[j4 * 4 + 2] = v.z; xv[j4 * 4 + 3] = v.w;
  }
  float s[21];
#pragma unroll
  for (int j = 0; j < 21; ++j) {
    const float* wr = (j < 20) ? (W0 + (size_t)j * DIN) : vr1;
    float acc = 0.f;
#pragma unroll
    for (int j4 = 0; j4 < 4; ++j4) {
      float4 wv = *(const float4*)(wr + (lane + j4 * 32) * 4);
      acc = fmaf(xv[j4 * 4 + 0], wv.x, acc);
      acc = fmaf(xv[j4 * 4 + 1], wv.y, acc);
      acc = fmaf(xv[j4 * 4 + 2], wv.z, acc);
      acc = fmaf(xv[j4 * 4 + 3], wv.w, acc);
    }
#pragma unroll
    for (int m = 1; m < 32; m <<= 1) acc += __shfl_xor(acc, m);
    s[j] = acc;
  }
  if (lane == 0) {
#pragma unroll
    for (int j = 0; j < 20; ++j) ms0[(size_t)node * DOUT + j] = s[j] + b0[j];
    er1[node] = s[20];
  }
}

// ---------- edge pass A: score + segment max ----------
__launch_bounds__(256)
__global__ void k_edge_max(const int* __restrict__ ei, const float* __restrict__ el,
                           const float* __restrict__ er, float* __restrict__ es,
                           u32* __restrict__ emax, int E) {
  int e = blockIdx.x * 256 + threadIdx.x;
  if (e >= E) return;
  int s = ei[e], d = ei[E + e];
  float v = el[s] + er[d];
  v = v >= 0.f ? v : 0.2f * v;   // leaky_relu 0.2
  es[e] = v;
  atomicMax(emax + d, encf(v));
}

// ---------- edge pass B: w = exp(e - max), segment sum ----------
__launch_bounds__(256)
__global__ void k_edge_exp(const int* __restrict__ ei, float* __restrict__ es,
                           const u32* __restrict__ emax, float* __restrict__ denom, int E) {
  int e = blockIdx.x * 256 + threadIdx.x;
  if (e >= E) return;
  int d = ei[E + e];
  float w = expf(es[e] - decf(emax[d]));
  es[e] = w;
  atomicAdd(denom + d, w);
}

// ---------- scatter 1: out1[dst] += w * xl1[src]  (128 cols, 2 edges/block) ----------
__launch_bounds__(256)
__global__ void k_scatter1(const int* __restrict__ ei, const float* __restrict__ es,
                           const float* __restrict__ xl1, float* __restrict__ out1, int E) {
  int eo = threadIdx.x >> 7;
  int c = threadIdx.x & 127;
  int e = blockIdx.x * 2 + eo;
  if (e >= E) return;
  int s = ei[e], d = ei[E + e];
  float wgt = es[e];
  atomicAdd(out1 + (size_t)d * HID + c, wgt * xl1[(size_t)s * HID + c]);
}

// ---------- per-node layer 2: h = ELU(out1/denom + b1); xl2 = h@W2l^T; el2, er2 ----------
__launch_bounds__(256)
__global__ void k_node2(const float* __restrict__ out1, const float* __restrict__ denom1,
                        const float* __restrict__ b1, const float* __restrict__ W2l,
                        const float* __restrict__ a2l, const float* __restrict__ vr2,
                        float* __restrict__ xl2, float* __restrict__ el2,
                        float* __restrict__ er2, int M) {
  int g = threadIdx.x >> 5, lane = threadIdx.x & 31;
  int node = blockIdx.x * 8 + g;
  if (node >= M) return;
  float dn = denom1[node] + 1e-16f;
  float4 v = *(const float4*)(out1 + (size_t)node * HID + lane * 4);
  float4 bb = *(const float4*)(b1 + lane * 4);
  float h[4] = {v.x / dn + bb.x, v.y / dn + bb.y, v.z / dn + bb.z, v.w / dn + bb.w};
#pragma unroll
  for (int t = 0; t < 4; ++t) h[t] = h[t] > 0.f ? h[t] : expm1f(h[t]);  // ELU
  float s[21];
#pragma unroll
  for (int j = 0; j < 21; ++j) {
    const float* wr = (j < 20) ? (W2l + (size_t)j * HID) : vr2;
    float4 wv = *(const float4*)(wr + lane * 4);
    float acc;
    acc = fmaf(h[0], wv.x, 0.f);
    acc = fmaf(h[1], wv.y, acc);
    acc = fmaf(h[2], wv.z, acc);
    acc = fmaf(h[3], wv.w, acc);
#pragma unroll
    for (int m = 1; m < 32; m <<= 1) acc += __shfl_xor(acc, m);
    s[j] = acc;
  }
  if (lane == 0) {
    float el = 0.f;
#pragma unroll
    for (int j = 0; j < 20; ++j) {
      xl2[(size_t)node * DOUT + j] = s[j];
      el = fmaf(s[j], a2l[j], el);
    }
    el2[node] = el;
    er2[node] = s[20];
  }
}

// ---------- scatter 2: out2[dst] += w * xl2[src]  (20 cols, 8 edges/block) ----------
__launch_bounds__(256)
__global__ void k_scatter2(const int* __restrict__ ei, const float* __restrict__ es,
                           const float* __restrict__ xl2, float* __restrict__ out2, int E) {
  int eo = threadIdx.x >> 5;
  int c = threadIdx.x & 31;
  int e = blockIdx.x * 8 + eo;
  if (e >= E || c >= DOUT) return;
  int s = ei[e], d = ei[E + e];
  float wgt = es[e];
  atomicAdd(out2 + (size_t)d * DOUT + c, wgt * xl2[(size_t)s * DOUT + c]);
}

// ---------- column max of ms0 (softmax axis=0) ----------
__launch_bounds__(256)
__global__ void k_colmax(const float* __restrict__ ms0, u32* __restrict__ colmaxU, int M) {
  float m[20];
#pragma unroll
  for (int j = 0; j < 20; ++j) m[j] = -INFINITY;
  int stride = gridDim.x * blockDim.x;
  for (int i = blockIdx.x * blockDim.x + threadIdx.x; i < M; i += stride) {
    const float4* row = (const float4*)(ms0 + (size_t)i * DOUT);
#pragma unroll
    for (int q = 0; q < 5; ++q) {
      float4 v = row[q];
      m[q * 4 + 0] = fmaxf(m[q * 4 + 0], v.x);
      m[q * 4 + 1] = fmaxf(m[q * 4 + 1], v.y);
      m[q * 4 + 2] = fmaxf(m[q * 4 + 2], v.z);
      m[q * 4 + 3] = fmaxf(m[q * 4 + 3], v.w);
    }
  }
#pragma unroll
  for (int j = 0; j < 20; ++j) {
#pragma unroll
    for (int k = 1; k < 64; k <<= 1) m[j] = fmaxf(m[j], __shfl_xor(m[j], k));
  }
  if ((threadIdx.x & 63) == 0) {
#pragma unroll
    for (int j = 0; j < 20; ++j) atomicMax(colmaxU + j, encf(m[j]));
  }
}

// ---------- column sum of exp(ms0 - colmax) ----------
__launch_bounds__(256)
__global__ void k_colsum(const float* __restrict__ ms0, const u32* __restrict__ colmaxU,
                         float* __restrict__ colsum, int M) {
  float cm[20], sm[20];
#pragma unroll
  for (int j = 0; j < 20; ++j) { cm[j] = decf(colmaxU[j]); sm[j] = 0.f; }
  int stride = gridDim.x * blockDim.x;
  for (int i = blockIdx.x * blockDim.x + threadIdx.x; i < M; i += stride) {
    const float4* row = (const float4*)(ms0 + (size_t)i * DOUT);
#pragma unroll
    for (int q = 0; q < 5; ++q) {
      float4 v = row[q];
      sm[q * 4 + 0] += expf(v.x - cm[q * 4 + 0]);
      sm[q * 4 + 1] += expf(v.y - cm[q * 4 + 1]);
      sm[q * 4 + 2] += expf(v.z - cm[q * 4 + 2]);
      sm[q * 4 + 3] += expf(v.w - cm[q * 4 + 3]);
    }
  }
#pragma unroll
  for (int j = 0; j < 20; ++j) {
#pragma unroll
    for (int k = 1; k < 64; k <<= 1) sm[j] += __shfl_xor(sm[j], k);
  }
  if ((threadIdx.x & 63) == 0) {
#pragma unroll
    for (int j = 0; j < 20; ++j) atomicAdd(colsum + j, sm[j]);
  }
}

// ---------- final: softmax(ms0,axis=0) * softmax(ms1,axis=1) ----------
__launch_bounds__(256)
__global__ void k_final(const float* __restrict__ ms0, const float* __restrict__ out2,
                        const float* __restrict__ denom2, const float* __restrict__ b2,
                        const u32* __restrict__ colmaxU, const float* __restrict__ colsum,
                        float* __restrict__ out, int M) {
  int i = blockIdx.x * 256 + threadIdx.x;
  if (i >= M) return;
  float dn = denom2[i] + 1e-16f;
  float ms1[20];
  const float4* r2 = (const float4*)(out2 + (size_t)i * DOUT);
#pragma unroll
  for (int q = 0; q < 5; ++q) {
    float4 v = r2[q];
    ms1[q * 4 + 0] = v.x / dn + b2[q * 4 + 0];
    ms1[q * 4 + 1] = v.y / dn + b2[q * 4 + 1];
    ms1[q * 4 + 2] = v.z / dn + b2[q * 4 + 2];
    ms1[q * 4 + 3] = v.w / dn + b2[q * 4 + 3];
  }
  float rmax = -INFINITY;
#pragma unroll
  for (int j = 0; j < 20; ++j) rmax = fmaxf(rmax, ms1[j]);
  float rsum = 0.f;
#pragma unroll
  for (int j = 0; j < 20; ++j) { ms1[j] = expf(ms1[j] - rmax); rsum += ms1[j]; }
  const float4* r0 = (const float4*)(ms0 + (size_t)i * DOUT);
  float o[20];
#pragma unroll
  for (int q = 0; q < 5; ++q) {
    float4 v = r0[q];
    o[q * 4 + 0] = expf(v.x - decf(colmaxU[q * 4 + 0])) / colsum[q * 4 + 0] * (ms1[q * 4 + 0] / rsum);
    o[q * 4 + 1] = expf(v.y - decf(colmaxU[q * 4 + 1])) / colsum[q * 4 + 1] * (ms1[q * 4 + 1] / rsum);
    o[q * 4 + 2] = expf(v.z - decf(colmaxU[q * 4 + 2])) / colsum[q * 4 + 2] * (ms1[q * 4 + 2] / rsum);
    o[q * 4 + 3] = expf(v.w - decf(colmaxU[q * 4 + 3])) / colsum[q * 4 + 3] * (ms1[q * 4 + 3] / rsum);
  }
  float4* po = (float4*)(out + (size_t)i * DOUT);
#pragma unroll
  for (int q = 0; q < 5; ++q)
    po[q] = make_float4(o[q * 4 + 0], o[q * 4 + 1], o[q * 4 + 2], o[q * 4 + 3]);
}

extern "C" void kernel_launch(void* const* d_in, const int* in_sizes, int n_in,
                              void* d_out, int out_size, void* d_ws, size_t ws_size,
                              hipStream_t stream) {
  const float* x   = (const float*)d_in[0];
  const int*   ei  = (const int*)d_in[1];   // [2,E] int32, src row then dst row
  const float* W0  = (const float*)d_in[2];
  const float* b0  = (const float*)d_in[3];
  const float* W1l = (const float*)d_in[4];
  const float* W1r = (const float*)d_in[5];
  const float* a1l = (const float*)d_in[6];
  const float* a1r = (const float*)d_in[7];
  const float* b1  = (const float*)d_in[8];
  const float* W2l = (const float*)d_in[9];
  const float* W2r = (const float*)d_in[10];
  const float* a2l = (const float*)d_in[11];
  const float* a2r = (const float*)d_in[12];
  const float* b2  = (const float*)d_in[13];
  const int M = in_sizes[0] / DIN;   // 50000
  const int E = in_sizes[1] / 2;     // 500000
  (void)n_in; (void)out_size; (void)ws_size;

  char* w = (char*)d_ws;
  size_t off = 0;
  auto alloc = [&](size_t bytes) -> void* {
    void* p = w + off;
    off += (bytes + 255) & ~(size_t)255;
    return p;
  };
  // total ~68 MB of workspace
  float* xl1     = (float*)alloc((size_t)M * HID * 4);
  float* el1     = (float*)alloc((size_t)M * 4);
  float* er1     = (float*)alloc((size_t)M * 4);
  float* ms0     = (float*)alloc((size_t)M * DOUT * 4);
  float* es1     = (float*)alloc((size_t)E * 4);
  u32*   emax1   = (u32*)alloc((size_t)M * 4);
  float* denom1  = (float*)alloc((size_t)M * 4);
  float* out1    = (float*)alloc((size_t)M * HID * 4);
  float* xl2     = (float*)alloc((size_t)M * DOUT * 4);
  float* el2     = (float*)alloc((size_t)M * 4);
  float* er2     = (float*)alloc((size_t)M * 4);
  float* es2     = (float*)alloc((size_t)E * 4);
  u32*   emax2   = (u32*)alloc((size_t)M * 4);
  float* denom2  = (float*)alloc((size_t)M * 4);
  float* out2    = (float*)alloc((size_t)M * DOUT * 4);
  u32*   colmaxU = (u32*)alloc(32 * 4);
  float* colsum  = (float*)alloc(32 * 4);
  float* vr1     = (float*)alloc(DIN * 4);
  float* vr2     = (float*)alloc(HID * 4);

  hipMemsetAsync(out1, 0, (size_t)M * HID * 4, stream);
  hipMemsetAsync(out2, 0, (size_t)M * DOUT * 4, stream);
  hipMemsetAsync(denom1, 0, (size_t)M * 4, stream);
  hipMemsetAsync(denom2, 0, (size_t)M * 4, stream);
  hipMemsetAsync(colsum, 0, 32 * 4, stream);

  k_prep<<<1, 256, 0, stream>>>(W1r, a1r, W2r, a2r, vr1, vr2);
  k_fill<<<256, 256, 0, stream>>>(emax1, emax2, colmaxU, M);

  k_gemm1<<<(M + 63) / 64, 256, 0, stream>>>(x, W1l, a1l, xl1, el1, M);
  k_node1<<<(M + 7) / 8, 256, 0, stream>>>(x, W0, b0, vr1, ms0, er1, M);

  k_edge_max<<<(E + 255) / 256, 256, 0, stream>>>(ei, el1, er1, es1, emax1, E);
  k_edge_exp<<<(E + 255) / 256, 256, 0, stream>>>(ei, es1, emax1, denom1, E);
  k_scatter1<<<(E + 1) / 2, 256, 0, stream>>>(ei, es1, xl1, out1, E);

  k_node2<<<(M + 7) / 8, 256, 0, stream>>>(out1, denom1, b1, W2l, a2l, vr2,
                                           xl2, el2, er2, M);

  k_edge_max<<<(E + 255) / 256, 256, 0, stream>>>(ei, el2, er2, es2, emax2, E);
  k_edge_exp<<<(E + 255) / 256, 256, 0, stream>>>(ei, es2, emax2, denom2, E);
  k_scatter2<<<(E + 7) / 8, 256, 0, stream>>>(ei, es2, xl2, out2, E);

  k_colmax<<<256, 256, 0, stream>>>(ms0, colmaxU, M);
  k_colsum<<<256, 256, 0, stream>>>(ms0, colmaxU, colsum, M);
  k_final<<<(M + 255) / 256, 256, 0, stream>>>(ms0, out2, denom2, b2, colmaxU,
                                               colsum, (float*)d_out, M);
}

// Round 2
// 718.677 us; speedup vs baseline: 1.6389x; 1.6389x over previous
//
#include <hip/hip_runtime.h>
#include <math.h>

#define DIN 512
#define HID 128
#define DOUT 20
#define NBLK_COL 200

// ---------- prep: vr1 = W1r^T @ a1r  (512), vr2 = W2r^T @ a2r (128) ----------
__global__ void k_prep(const float* __restrict__ W1r, const float* __restrict__ a1r,
                       const float* __restrict__ W2r, const float* __restrict__ a2r,
                       float* __restrict__ vr1, float* __restrict__ vr2) {
  int t = threadIdx.x;
  for (int k = t; k < DIN; k += 256) {
    float s = 0.f;
    for (int c = 0; c < HID; ++c) s = fmaf(a1r[c], W1r[c * DIN + k], s);
    vr1[k] = s;
  }
  if (t < HID) {
    float s = 0.f;
    for (int c = 0; c < DOUT; ++c) s = fmaf(a2r[c], W2r[c * HID + t], s);
    vr2[t] = s;
  }
}

// ---------- GEMM: xl1 = x @ W1l^T  [M,128], epilogue el1 = xl1 @ a1l ----------
__launch_bounds__(256)
__global__ void k_gemm1(const float* __restrict__ x, const float* __restrict__ W,
                        const float* __restrict__ al, float* __restrict__ xl1,
                        float* __restrict__ el1, int M) {
  __shared__ float xs[64][33];    // 64 rows x 32 k (+1 pad)
  __shared__ float ws[32][132];   // 32 k x 128 cols (+4 pad, keeps rows 16B-aligned)
  const int tid = threadIdx.x;
  const int tx = tid & 15;        // col group: cols tx*8 .. tx*8+7
  const int ty = tid >> 4;        // row group: rows ty*4 .. ty*4+3
  const int brow = blockIdx.x * 64;
  float acc[4][8] = {};
  for (int k0 = 0; k0 < DIN; k0 += 32) {
#pragma unroll
    for (int i = 0; i < 2; ++i) {          // x tile: 512 float4 slots
      int s = tid * 2 + i;
      int r = s >> 3, k4 = s & 7;
      float4 v = make_float4(0.f, 0.f, 0.f, 0.f);
      int grow = brow + r;
      if (grow < M) v = *(const float4*)(x + (size_t)grow * DIN + k0 + k4 * 4);
      xs[r][k4 * 4 + 0] = v.x; xs[r][k4 * 4 + 1] = v.y;
      xs[r][k4 * 4 + 2] = v.z; xs[r][k4 * 4 + 3] = v.w;
    }
#pragma unroll
    for (int i = 0; i < 4; ++i) {          // W tile: 1024 float4 slots, transposed
      int s = tid * 4 + i;
      int c = s >> 3, k4 = s & 7;
      float4 v = *(const float4*)(W + (size_t)c * DIN + k0 + k4 * 4);
      ws[k4 * 4 + 0][c] = v.x; ws[k4 * 4 + 1][c] = v.y;
      ws[k4 * 4 + 2][c] = v.z; ws[k4 * 4 + 3][c] = v.w;
    }
    __syncthreads();
#pragma unroll
    for (int kk = 0; kk < 32; ++kk) {
      float xv[4];
#pragma unroll
      for (int r = 0; r < 4; ++r) xv[r] = xs[ty * 4 + r][kk];
      float4 w0 = *(const float4*)&ws[kk][tx * 8];
      float4 w1 = *(const float4*)&ws[kk][tx * 8 + 4];
      float wv[8] = {w0.x, w0.y, w0.z, w0.w, w1.x, w1.y, w1.z, w1.w};
#pragma unroll
      for (int r = 0; r < 4; ++r)
#pragma unroll
        for (int c = 0; c < 8; ++c)
          acc[r][c] = fmaf(xv[r], wv[c], acc[r][c]);
    }
    __syncthreads();
  }
  float alv[8];
#pragma unroll
  for (int c = 0; c < 8; ++c) alv[c] = al[tx * 8 + c];
#pragma unroll
  for (int r = 0; r < 4; ++r) {
    int grow = brow + ty * 4 + r;
    float part = 0.f;
#pragma unroll
    for (int c = 0; c < 8; ++c) part = fmaf(acc[r][c], alv[c], part);
    part += __shfl_xor(part, 1);
    part += __shfl_xor(part, 2);
    part += __shfl_xor(part, 4);
    part += __shfl_xor(part, 8);   // reduce over the 16 tx lanes
    if (grow < M) {
      *(float4*)(xl1 + (size_t)grow * HID + tx * 8) =
          make_float4(acc[r][0], acc[r][1], acc[r][2], acc[r][3]);
      *(float4*)(xl1 + (size_t)grow * HID + tx * 8 + 4) =
          make_float4(acc[r][4], acc[r][5], acc[r][6], acc[r][7]);
      if (tx == 0) el1[grow] = part;
    }
  }
}

// ---------- per-node: ms0 = x@W0^T + b0, er1 = x@vr1 (32 lanes per node) ----------
__launch_bounds__(256)
__global__ void k_node1(const float* __restrict__ x, const float* __restrict__ W0,
                        const float* __restrict__ b0, const float* __restrict__ vr1,
                        float* __restrict__ ms0, float* __restrict__ er1, int M) {
  int g = threadIdx.x >> 5, lane = threadIdx.x & 31;
  int node = blockIdx.x * 8 + g;
  if (node >= M) return;
  float xv[16];
#pragma unroll
  for (int j4 = 0; j4 < 4; ++j4) {
    float4 v = *(const float4*)(x + (size_t)node * DIN + (lane + j4 * 32) * 4);
    xv[j4 * 4 + 0] = v.x; xv[j4 * 4 + 1] = v.y;
    xv[j4 * 4 + 2] = v.z; xv[j4 * 4 + 3] = v.w;
  }
  float s[21];
#pragma unroll
  for (int j = 0; j < 21; ++j) {
    const float* wr = (j < 20) ? (W0 + (size_t)j * DIN) : vr1;
    float acc = 0.f;
#pragma unroll
    for (int j4 = 0; j4 < 4; ++j4) {
      float4 wv = *(const float4*)(wr + (lane + j4 * 32) * 4);
      acc = fmaf(xv[j4 * 4 + 0], wv.x, acc);
      acc = fmaf(xv[j4 * 4 + 1], wv.y, acc);
      acc = fmaf(xv[j4 * 4 + 2], wv.z, acc);
      acc = fmaf(xv[j4 * 4 + 3], wv.w, acc);
    }
#pragma unroll
    for (int m = 1; m < 32; m <<= 1) acc += __shfl_xor(acc, m);
    s[j] = acc;
  }
  if (lane == 0) {
#pragma unroll
    for (int j = 0; j < 20; ++j) ms0[(size_t)node * DOUT + j] = s[j] + b0[j];
    er1[node] = s[20];
  }
}

// ---------- fused edge layer 1: w = exp(leaky(el[s]+er[d])); denom; scatter ----------
// 2 edges per 256-thread block, 128 cols per edge.
__launch_bounds__(256)
__global__ void k_edge1(const int* __restrict__ ei, const float* __restrict__ el,
                        const float* __restrict__ er, const float* __restrict__ xl1,
                        float* __restrict__ out1, float* __restrict__ denom, int E) {
  int eo = threadIdx.x >> 7;
  int c = threadIdx.x & 127;
  int e = blockIdx.x * 2 + eo;
  if (e >= E) return;
  int s = ei[e], d = ei[E + e];
  float v = el[s] + er[d];
  v = v >= 0.f ? v : 0.2f * v;   // leaky_relu 0.2
  float w = expf(v);             // no max-subtraction: v bounded (~|8|), fp32-safe
  atomicAdd(out1 + (size_t)d * HID + c, w * xl1[(size_t)s * HID + c]);
  if (c == 0) atomicAdd(denom + d, w);
}

// ---------- per-node layer 2: h = ELU(out1/denom + b1); xl2 = h@W2l^T; el2, er2 ----------
__launch_bounds__(256)
__global__ void k_node2(const float* __restrict__ out1, const float* __restrict__ denom1,
                        const float* __restrict__ b1, const float* __restrict__ W2l,
                        const float* __restrict__ a2l, const float* __restrict__ vr2,
                        float* __restrict__ xl2, float* __restrict__ el2,
                        float* __restrict__ er2, int M) {
  int g = threadIdx.x >> 5, lane = threadIdx.x & 31;
  int node = blockIdx.x * 8 + g;
  if (node >= M) return;
  float dn = denom1[node] + 1e-16f;
  float4 v = *(const float4*)(out1 + (size_t)node * HID + lane * 4);
  float4 bb = *(const float4*)(b1 + lane * 4);
  float h[4] = {v.x / dn + bb.x, v.y / dn + bb.y, v.z / dn + bb.z, v.w / dn + bb.w};
#pragma unroll
  for (int t = 0; t < 4; ++t) h[t] = h[t] > 0.f ? h[t] : expm1f(h[t]);  // ELU
  float s[21];
#pragma unroll
  for (int j = 0; j < 21; ++j) {
    const float* wr = (j < 20) ? (W2l + (size_t)j * HID) : vr2;
    float4 wv = *(const float4*)(wr + lane * 4);
    float acc;
    acc = fmaf(h[0], wv.x, 0.f);
    acc = fmaf(h[1], wv.y, acc);
    acc = fmaf(h[2], wv.z, acc);
    acc = fmaf(h[3], wv.w, acc);
#pragma unroll
    for (int m = 1; m < 32; m <<= 1) acc += __shfl_xor(acc, m);
    s[j] = acc;
  }
  if (lane == 0) {
    float el = 0.f;
#pragma unroll
    for (int j = 0; j < 20; ++j) {
      xl2[(size_t)node * DOUT + j] = s[j];
      el = fmaf(s[j], a2l[j], el);
    }
    el2[node] = el;
    er2[node] = s[20];
  }
}

// ---------- fused edge layer 2: 8 edges per block, 32 lanes per edge ----------
__launch_bounds__(256)
__global__ void k_edge2(const int* __restrict__ ei, const float* __restrict__ el,
                        const float* __restrict__ er, const float* __restrict__ xl2,
                        float* __restrict__ out2, float* __restrict__ denom, int E) {
  int eo = threadIdx.x >> 5;
  int c = threadIdx.x & 31;
  int e = blockIdx.x * 8 + eo;
  if (e >= E) return;
  int s = ei[e], d = ei[E + e];
  float v = el[s] + er[d];
  v = v >= 0.f ? v : 0.2f * v;
  float w = expf(v);
  if (c == 0) atomicAdd(denom + d, w);
  if (c < DOUT) atomicAdd(out2 + (size_t)d * DOUT + c, w * xl2[(size_t)s * DOUT + c]);
}

// ---------- column sum of exp(ms0): stage 1, per-block partials (no atomics) ----------
__launch_bounds__(256)
__global__ void k_colsum1(const float* __restrict__ ms0, float* __restrict__ partial, int M) {
  __shared__ float lds[4][20];
  float sm[20];
#pragma unroll
  for (int j = 0; j < 20; ++j) sm[j] = 0.f;
  int stride = gridDim.x * blockDim.x;
  for (int i = blockIdx.x * blockDim.x + threadIdx.x; i < M; i += stride) {
    const float4* row = (const float4*)(ms0 + (size_t)i * DOUT);
#pragma unroll
    for (int q = 0; q < 5; ++q) {
      float4 v = row[q];
      sm[q * 4 + 0] += expf(v.x);
      sm[q * 4 + 1] += expf(v.y);
      sm[q * 4 + 2] += expf(v.z);
      sm[q * 4 + 3] += expf(v.w);
    }
  }
#pragma unroll
  for (int j = 0; j < 20; ++j) {
#pragma unroll
    for (int k = 1; k < 64; k <<= 1) sm[j] += __shfl_xor(sm[j], k);
  }
  int wave = threadIdx.x >> 6, lane = threadIdx.x & 63;
  if (lane == 0) {
#pragma unroll
    for (int j = 0; j < 20; ++j) lds[wave][j] = sm[j];
  }
  __syncthreads();
  if (threadIdx.x < 20)
    partial[blockIdx.x * 20 + threadIdx.x] =
        lds[0][threadIdx.x] + lds[1][threadIdx.x] + lds[2][threadIdx.x] + lds[3][threadIdx.x];
}

// ---------- column sum stage 2: one block folds NBLK_COL partials ----------
__global__ void k_colsum2(const float* __restrict__ partial, float* __restrict__ colsum) {
  int j = threadIdx.x;
  if (j < 20) {
    float s = 0.f;
    for (int b = 0; b < NBLK_COL; ++b) s += partial[b * 20 + j];
    colsum[j] = s;
  }
}

// ---------- final: softmax(ms0,axis=0) * softmax(ms1,axis=1) ----------
__launch_bounds__(256)
__global__ void k_final(const float* __restrict__ ms0, const float* __restrict__ out2,
                        const float* __restrict__ denom2, const float* __restrict__ b2,
                        const float* __restrict__ colsum, float* __restrict__ out, int M) {
  int i = blockIdx.x * 256 + threadIdx.x;
  if (i >= M) return;
  float dn = denom2[i] + 1e-16f;
  float ms1[20];
  const float4* r2 = (const float4*)(out2 + (size_t)i * DOUT);
#pragma unroll
  for (int q = 0; q < 5; ++q) {
    float4 v = r2[q];
    ms1[q * 4 + 0] = v.x / dn + b2[q * 4 + 0];
    ms1[q * 4 + 1] = v.y / dn + b2[q * 4 + 1];
    ms1[q * 4 + 2] = v.z / dn + b2[q * 4 + 2];
    ms1[q * 4 + 3] = v.w / dn + b2[q * 4 + 3];
  }
  float rmax = -INFINITY;
#pragma unroll
  for (int j = 0; j < 20; ++j) rmax = fmaxf(rmax, ms1[j]);
  float rsum = 0.f;
#pragma unroll
  for (int j = 0; j < 20; ++j) { ms1[j] = expf(ms1[j] - rmax); rsum += ms1[j]; }
  const float4* r0 = (const float4*)(ms0 + (size_t)i * DOUT);
  float o[20];
#pragma unroll
  for (int q = 0; q < 5; ++q) {
    float4 v = r0[q];
    o[q * 4 + 0] = expf(v.x) / colsum[q * 4 + 0] * (ms1[q * 4 + 0] / rsum);
    o[q * 4 + 1] = expf(v.y) / colsum[q * 4 + 1] * (ms1[q * 4 + 1] / rsum);
    o[q * 4 + 2] = expf(v.z) / colsum[q * 4 + 2] * (ms1[q * 4 + 2] / rsum);
    o[q * 4 + 3] = expf(v.w) / colsum[q * 4 + 3] * (ms1[q * 4 + 3] / rsum);
  }
  float4* po = (float4*)(out + (size_t)i * DOUT);
#pragma unroll
  for (int q = 0; q < 5; ++q)
    po[q] = make_float4(o[q * 4 + 0], o[q * 4 + 1], o[q * 4 + 2], o[q * 4 + 3]);
}

extern "C" void kernel_launch(void* const* d_in, const int* in_sizes, int n_in,
                              void* d_out, int out_size, void* d_ws, size_t ws_size,
                              hipStream_t stream) {
  const float* x   = (const float*)d_in[0];
  const int*   ei  = (const int*)d_in[1];   // [2,E] int32, src row then dst row
  const float* W0  = (const float*)d_in[2];
  const float* b0  = (const float*)d_in[3];
  const float* W1l = (const float*)d_in[4];
  const float* W1r = (const float*)d_in[5];
  const float* a1l = (const float*)d_in[6];
  const float* a1r = (const float*)d_in[7];
  const float* b1  = (const float*)d_in[8];
  const float* W2l = (const float*)d_in[9];
  const float* W2r = (const float*)d_in[10];
  const float* a2l = (const float*)d_in[11];
  const float* a2r = (const float*)d_in[12];
  const float* b2  = (const float*)d_in[13];
  const int M = in_sizes[0] / DIN;   // 50000
  const int E = in_sizes[1] / 2;     // 500000
  (void)n_in; (void)out_size; (void)ws_size;

  char* w = (char*)d_ws;
  size_t off = 0;
  auto alloc = [&](size_t bytes) -> void* {
    void* p = w + off;
    off += (bytes + 255) & ~(size_t)255;
    return p;
  };
  float* xl1     = (float*)alloc((size_t)M * HID * 4);
  float* el1     = (float*)alloc((size_t)M * 4);
  float* er1     = (float*)alloc((size_t)M * 4);
  float* ms0     = (float*)alloc((size_t)M * DOUT * 4);
  float* denom1  = (float*)alloc((size_t)M * 4);
  float* out1    = (float*)alloc((size_t)M * HID * 4);
  float* xl2     = (float*)alloc((size_t)M * DOUT * 4);
  float* el2     = (float*)alloc((size_t)M * 4);
  float* er2     = (float*)alloc((size_t)M * 4);
  float* denom2  = (float*)alloc((size_t)M * 4);
  float* out2    = (float*)alloc((size_t)M * DOUT * 4);
  float* partial = (float*)alloc((size_t)NBLK_COL * 20 * 4);
  float* colsum  = (float*)alloc(32 * 4);
  float* vr1     = (float*)alloc(DIN * 4);
  float* vr2     = (float*)alloc(HID * 4);

  hipMemsetAsync(out1, 0, (size_t)M * HID * 4, stream);
  hipMemsetAsync(out2, 0, (size_t)M * DOUT * 4, stream);
  hipMemsetAsync(denom1, 0, (size_t)M * 4, stream);
  hipMemsetAsync(denom2, 0, (size_t)M * 4, stream);

  k_prep<<<1, 256, 0, stream>>>(W1r, a1r, W2r, a2r, vr1, vr2);

  k_gemm1<<<(M + 63) / 64, 256, 0, stream>>>(x, W1l, a1l, xl1, el1, M);
  k_node1<<<(M + 7) / 8, 256, 0, stream>>>(x, W0, b0, vr1, ms0, er1, M);

  k_edge1<<<(E + 1) / 2, 256, 0, stream>>>(ei, el1, er1, xl1, out1, denom1, E);

  k_node2<<<(M + 7) / 8, 256, 0, stream>>>(out1, denom1, b1, W2l, a2l, vr2,
                                           xl2, el2, er2, M);

  k_edge2<<<(E + 7) / 8, 256, 0, stream>>>(ei, el2, er2, xl2, out2, denom2, E);

  k_colsum1<<<NBLK_COL, 256, 0, stream>>>(ms0, partial, M);
  k_colsum2<<<1, 64, 0, stream>>>(partial, colsum);
  k_final<<<(M + 255) / 256, 256, 0, stream>>>(ms0, out2, denom2, b2,
                                               colsum, (float*)d_out, M);
}

// Round 4
// 635.818 us; speedup vs baseline: 1.8525x; 1.1303x over previous
//
#include <hip/hip_runtime.h>
#include <math.h>

#define DIN 512
#define HID 128
#define DOUT 20
#define NBLK_COL 200

// ---------- prep: vr1 = W1r^T @ a1r  (512), vr2 = W2r^T @ a2r (128) ----------
__global__ void k_prep(const float* __restrict__ W1r, const float* __restrict__ a1r,
                       const float* __restrict__ W2r, const float* __restrict__ a2r,
                       float* __restrict__ vr1, float* __restrict__ vr2) {
  int t = threadIdx.x;
  for (int k = t; k < DIN; k += 256) {
    float s = 0.f;
    for (int c = 0; c < HID; ++c) s = fmaf(a1r[c], W1r[c * DIN + k], s);
    vr1[k] = s;
  }
  if (t < HID) {
    float s = 0.f;
    for (int c = 0; c < DOUT; ++c) s = fmaf(a2r[c], W2r[c * HID + t], s);
    vr2[t] = s;
  }
}

// ---------- CSR build: histogram of dst ----------
__global__ void k_hist(const int* __restrict__ ei, int* __restrict__ deg, int E) {
  int stride = gridDim.x * blockDim.x;
  for (int e = blockIdx.x * blockDim.x + threadIdx.x; e < E; e += stride)
    atomicAdd(deg + ei[E + e], 1);
}

// ---------- CSR build: exclusive scan (one 1024-thread block) ----------
__launch_bounds__(1024)
__global__ void k_scan(const int* __restrict__ deg, int* __restrict__ rowptr,
                       int* __restrict__ cursor, int M) {
  __shared__ int part[1024];
  int t = threadIdx.x;
  int chunk = (M + 1023) >> 10;
  int lo = t * chunk, hi = min(lo + chunk, M);
  int s = 0;
  for (int i = lo; i < hi; ++i) s += deg[i];
  part[t] = s;
  __syncthreads();
  for (int off = 1; off < 1024; off <<= 1) {
    int v = (t >= off) ? part[t - off] : 0;
    __syncthreads();
    part[t] += v;
    __syncthreads();
  }
  int run = (t == 0) ? 0 : part[t - 1];
  for (int i = lo; i < hi; ++i) {
    rowptr[i] = run; cursor[i] = run;
    run += deg[i];
  }
  if (t == 1023) rowptr[M] = run;
}

// ---------- CSR build: bucket srcs by dst ----------
__global__ void k_csr(const int* __restrict__ ei, int* __restrict__ cursor,
                      int* __restrict__ csr_src, int E) {
  int stride = gridDim.x * blockDim.x;
  for (int e = blockIdx.x * blockDim.x + threadIdx.x; e < E; e += stride) {
    int d = ei[E + e];
    int p = atomicAdd(cursor + d, 1);
    csr_src[p] = ei[e];
  }
}

// ---------- GEMM: xl1 = x @ W1l^T  [M,128], epilogue el1 = xl1 @ a1l ----------
__launch_bounds__(256)
__global__ void k_gemm1(const float* __restrict__ x, const float* __restrict__ W,
                        const float* __restrict__ al, float* __restrict__ xl1,
                        float* __restrict__ el1, int M) {
  __shared__ float xs[64][33];
  __shared__ float ws[32][132];
  const int tid = threadIdx.x;
  const int tx = tid & 15;
  const int ty = tid >> 4;
  const int brow = blockIdx.x * 64;
  float acc[4][8] = {};
  for (int k0 = 0; k0 < DIN; k0 += 32) {
#pragma unroll
    for (int i = 0; i < 2; ++i) {
      int s = tid * 2 + i;
      int r = s >> 3, k4 = s & 7;
      float4 v = make_float4(0.f, 0.f, 0.f, 0.f);
      int grow = brow + r;
      if (grow < M) v = *(const float4*)(x + (size_t)grow * DIN + k0 + k4 * 4);
      xs[r][k4 * 4 + 0] = v.x; xs[r][k4 * 4 + 1] = v.y;
      xs[r][k4 * 4 + 2] = v.z; xs[r][k4 * 4 + 3] = v.w;
    }
#pragma unroll
    for (int i = 0; i < 4; ++i) {
      int s = tid * 4 + i;
      int c = s >> 3, k4 = s & 7;
      float4 v = *(const float4*)(W + (size_t)c * DIN + k0 + k4 * 4);
      ws[k4 * 4 + 0][c] = v.x; ws[k4 * 4 + 1][c] = v.y;
      ws[k4 * 4 + 2][c] = v.z; ws[k4 * 4 + 3][c] = v.w;
    }
    __syncthreads();
#pragma unroll
    for (int kk = 0; kk < 32; ++kk) {
      float xv[4];
#pragma unroll
      for (int r = 0; r < 4; ++r) xv[r] = xs[ty * 4 + r][kk];
      float4 w0 = *(const float4*)&ws[kk][tx * 8];
      float4 w1 = *(const float4*)&ws[kk][tx * 8 + 4];
      float wv[8] = {w0.x, w0.y, w0.z, w0.w, w1.x, w1.y, w1.z, w1.w};
#pragma unroll
      for (int r = 0; r < 4; ++r)
#pragma unroll
        for (int c = 0; c < 8; ++c)
          acc[r][c] = fmaf(xv[r], wv[c], acc[r][c]);
    }
    __syncthreads();
  }
  float alv[8];
#pragma unroll
  for (int c = 0; c < 8; ++c) alv[c] = al[tx * 8 + c];
#pragma unroll
  for (int r = 0; r < 4; ++r) {
    int grow = brow + ty * 4 + r;
    float part = 0.f;
#pragma unroll
    for (int c = 0; c < 8; ++c) part = fmaf(acc[r][c], alv[c], part);
    part += __shfl_xor(part, 1);
    part += __shfl_xor(part, 2);
    part += __shfl_xor(part, 4);
    part += __shfl_xor(part, 8);
    if (grow < M) {
      *(float4*)(xl1 + (size_t)grow * HID + tx * 8) =
          make_float4(acc[r][0], acc[r][1], acc[r][2], acc[r][3]);
      *(float4*)(xl1 + (size_t)grow * HID + tx * 8 + 4) =
          make_float4(acc[r][4], acc[r][5], acc[r][6], acc[r][7]);
      if (tx == 0) el1[grow] = part;
    }
  }
}

// ---------- per-node: ms0 = x@W0^T + b0, er1 = x@vr1 (32 lanes per node) ----------
__launch_bounds__(256)
__global__ void k_node1(const float* __restrict__ x, const float* __restrict__ W0,
                        const float* __restrict__ b0, const float* __restrict__ vr1,
                        float* __restrict__ ms0, float* __restrict__ er1, int M) {
  int g = threadIdx.x >> 5, lane = threadIdx.x & 31;
  int node = blockIdx.x * 8 + g;
  if (node >= M) return;
  float xv[16];
#pragma unroll
  for (int j4 = 0; j4 < 4; ++j4) {
    float4 v = *(const float4*)(x + (size_t)node * DIN + (lane + j4 * 32) * 4);
    xv[j4 * 4 + 0] = v.x; xv[j4 * 4 + 1] = v.y;
    xv[j4 * 4 + 2] = v.z; xv[j4 * 4 + 3] = v.w;
  }
  float s[21];
#pragma unroll
  for (int j = 0; j < 21; ++j) {
    const float* wr = (j < 20) ? (W0 + (size_t)j * DIN) : vr1;
    float acc = 0.f;
#pragma unroll
    for (int j4 = 0; j4 < 4; ++j4) {
      float4 wv = *(const float4*)(wr + (lane + j4 * 32) * 4);
      acc = fmaf(xv[j4 * 4 + 0], wv.x, acc);
      acc = fmaf(xv[j4 * 4 + 1], wv.y, acc);
      acc = fmaf(xv[j4 * 4 + 2], wv.z, acc);
      acc = fmaf(xv[j4 * 4 + 3], wv.w, acc);
    }
#pragma unroll
    for (int m = 1; m < 32; m <<= 1) acc += __shfl_xor(acc, m);
    s[j] = acc;
  }
  if (lane == 0) {
#pragma unroll
    for (int j = 0; j < 20; ++j) ms0[(size_t)node * DOUT + j] = s[j] + b0[j];
    er1[node] = s[20];
  }
}

// ---------- gather layer 1: 64 lanes per dst node, 2 cols per lane ----------
// out1[d] = (sum_j w_j * xl1[src_j]) / (sum_j w_j + 1e-16)   (pre-normalized)
__launch_bounds__(256)
__global__ void k_gath1(const int* __restrict__ rowptr, const int* __restrict__ csr_src,
                        const float* __restrict__ el, const float* __restrict__ er,
                        const float* __restrict__ xl1, float* __restrict__ out1, int M) {
  int g = threadIdx.x >> 6, lane = threadIdx.x & 63;
  int d = blockIdx.x * 4 + g;
  if (d >= M) return;
  int lo = rowptr[d], hi = rowptr[d + 1];
  float erd = er[d];
  float a0 = 0.f, a1 = 0.f, wsum = 0.f;
  for (int j = lo; j < hi; ++j) {
    int s = csr_src[j];                      // broadcast across wave
    float v = el[s] + erd;
    v = v >= 0.f ? v : 0.2f * v;             // leaky_relu 0.2
    float w = expf(v);                       // bounded, no max-sub needed
    wsum += w;
    float2 xv = *(const float2*)(xl1 + (size_t)s * HID + lane * 2);
    a0 = fmaf(w, xv.x, a0);
    a1 = fmaf(w, xv.y, a1);
  }
  float inv = 1.f / (wsum + 1e-16f);
  *(float2*)(out1 + (size_t)d * HID + lane * 2) = make_float2(a0 * inv, a1 * inv);
}

// ---------- per-node layer 2: h = ELU(out1 + b1); xl2 = h@W2l^T; el2, er2 ----------
__launch_bounds__(256)
__global__ void k_node2(const float* __restrict__ out1, const float* __restrict__ b1,
                        const float* __restrict__ W2l, const float* __restrict__ a2l,
                        const float* __restrict__ vr2, float* __restrict__ xl2,
                        float* __restrict__ el2, float* __restrict__ er2, int M) {
  int g = threadIdx.x >> 5, lane = threadIdx.x & 31;
  int node = blockIdx.x * 8 + g;
  if (node >= M) return;
  float4 v = *(const float4*)(out1 + (size_t)node * HID + lane * 4);
  float4 bb = *(const float4*)(b1 + lane * 4);
  float h[4] = {v.x + bb.x, v.y + bb.y, v.z + bb.z, v.w + bb.w};
#pragma unroll
  for (int t = 0; t < 4; ++t) h[t] = h[t] > 0.f ? h[t] : expm1f(h[t]);  // ELU
  float s[21];
#pragma unroll
  for (int j = 0; j < 21; ++j) {
    const float* wr = (j < 20) ? (W2l + (size_t)j * HID) : vr2;
    float4 wv = *(const float4*)(wr + lane * 4);
    float acc;
    acc = fmaf(h[0], wv.x, 0.f);
    acc = fmaf(h[1], wv.y, acc);
    acc = fmaf(h[2], wv.z, acc);
    acc = fmaf(h[3], wv.w, acc);
#pragma unroll
    for (int m = 1; m < 32; m <<= 1) acc += __shfl_xor(acc, m);
    s[j] = acc;
  }
  if (lane == 0) {
    float el = 0.f;
#pragma unroll
    for (int j = 0; j < 20; ++j) {
      xl2[(size_t)node * DOUT + j] = s[j];
      el = fmaf(s[j], a2l[j], el);
    }
    el2[node] = el;
    er2[node] = s[20];
  }
}

// ---------- gather layer 2: 32 lanes per dst node, 20 active cols ----------
__launch_bounds__(256)
__global__ void k_gath2(const int* __restrict__ rowptr, const int* __restrict__ csr_src,
                        const float* __restrict__ el, const float* __restrict__ er,
                        const float* __restrict__ xl2, float* __restrict__ out2, int M) {
  int g = threadIdx.x >> 5, lane = threadIdx.x & 31;
  int d = blockIdx.x * 8 + g;
  if (d >= M) return;
  int lo = rowptr[d], hi = rowptr[d + 1];
  float erd = er[d];
  float acc = 0.f, wsum = 0.f;
  for (int j = lo; j < hi; ++j) {
    int s = csr_src[j];
    float v = el[s] + erd;
    v = v >= 0.f ? v : 0.2f * v;
    float w = expf(v);
    wsum += w;
    if (lane < DOUT) acc = fmaf(w, xl2[(size_t)s * DOUT + lane], acc);
  }
  if (lane < DOUT) out2[(size_t)d * DOUT + lane] = acc / (wsum + 1e-16f);
}

// ---------- column sum of exp(ms0): stage 1, per-block partials ----------
__launch_bounds__(256)
__global__ void k_colsum1(const float* __restrict__ ms0, float* __restrict__ partial, int M) {
  __shared__ float lds[4][20];
  float sm[20];
#pragma unroll
  for (int j = 0; j < 20; ++j) sm[j] = 0.f;
  int stride = gridDim.x * blockDim.x;
  for (int i = blockIdx.x * blockDim.x + threadIdx.x; i < M; i += stride) {
    const float4* row = (const float4*)(ms0 + (size_t)i * DOUT);
#pragma unroll
    for (int q = 0; q < 5; ++q) {
      float4 v = row[q];
      sm[q * 4 + 0] += expf(v.x);
      sm[q * 4 + 1] += expf(v.y);
      sm[q * 4 + 2] += expf(v.z);
      sm[q * 4 + 3] += expf(v.w);
    }
  }
#pragma unroll
  for (int j = 0; j < 20; ++j) {
#pragma unroll
    for (int k = 1; k < 64; k <<= 1) sm[j] += __shfl_xor(sm[j], k);
  }
  int wave = threadIdx.x >> 6, lane = threadIdx.x & 63;
  if (lane == 0) {
#pragma unroll
    for (int j = 0; j < 20; ++j) lds[wave][j] = sm[j];
  }
  __syncthreads();
  if (threadIdx.x < 20)
    partial[blockIdx.x * 20 + threadIdx.x] =
        lds[0][threadIdx.x] + lds[1][threadIdx.x] + lds[2][threadIdx.x] + lds[3][threadIdx.x];
}

__global__ void k_colsum2(const float* __restrict__ partial, float* __restrict__ colsum) {
  int j = threadIdx.x;
  if (j < 20) {
    float s = 0.f;
    for (int b = 0; b < NBLK_COL; ++b) s += partial[b * 20 + j];
    colsum[j] = s;
  }
}

// ---------- final: softmax(ms0,axis=0) * softmax(ms1,axis=1) ----------
__launch_bounds__(256)
__global__ void k_final(const float* __restrict__ ms0, const float* __restrict__ out2,
                        const float* __restrict__ b2, const float* __restrict__ colsum,
                        float* __restrict__ out, int M) {
  int i = blockIdx.x * 256 + threadIdx.x;
  if (i >= M) return;
  float ms1[20];
  const float4* r2 = (const float4*)(out2 + (size_t)i * DOUT);
#pragma unroll
  for (int q = 0; q < 5; ++q) {
    float4 v = r2[q];
    ms1[q * 4 + 0] = v.x + b2[q * 4 + 0];
    ms1[q * 4 + 1] = v.y + b2[q * 4 + 1];
    ms1[q * 4 + 2] = v.z + b2[q * 4 + 2];
    ms1[q * 4 + 3] = v.w + b2[q * 4 + 3];
  }
  float rmax = -INFINITY;
#pragma unroll
  for (int j = 0; j < 20; ++j) rmax = fmaxf(rmax, ms1[j]);
  float rsum = 0.f;
#pragma unroll
  for (int j = 0; j < 20; ++j) { ms1[j] = expf(ms1[j] - rmax); rsum += ms1[j]; }
  const float4* r0 = (const float4*)(ms0 + (size_t)i * DOUT);
  float o[20];
#pragma unroll
  for (int q = 0; q < 5; ++q) {
    float4 v = r0[q];
    o[q * 4 + 0] = expf(v.x) / colsum[q * 4 + 0] * (ms1[q * 4 + 0] / rsum);
    o[q * 4 + 1] = expf(v.y) / colsum[q * 4 + 1] * (ms1[q * 4 + 1] / rsum);
    o[q * 4 + 2] = expf(v.z) / colsum[q * 4 + 2] * (ms1[q * 4 + 2] / rsum);
    o[q * 4 + 3] = expf(v.w) / colsum[q * 4 + 3] * (ms1[q * 4 + 3] / rsum);
  }
  float4* po = (float4*)(out + (size_t)i * DOUT);
#pragma unroll
  for (int q = 0; q < 5; ++q)
    po[q] = make_float4(o[q * 4 + 0], o[q * 4 + 1], o[q * 4 + 2], o[q * 4 + 3]);
}

extern "C" void kernel_launch(void* const* d_in, const int* in_sizes, int n_in,
                              void* d_out, int out_size, void* d_ws, size_t ws_size,
                              hipStream_t stream) {
  const float* x   = (const float*)d_in[0];
  const int*   ei  = (const int*)d_in[1];
  const float* W0  = (const float*)d_in[2];
  const float* b0  = (const float*)d_in[3];
  const float* W1l = (const float*)d_in[4];
  const float* W1r = (const float*)d_in[5];
  const float* a1l = (const float*)d_in[6];
  const float* a1r = (const float*)d_in[7];
  const float* b1  = (const float*)d_in[8];
  const float* W2l = (const float*)d_in[9];
  const float* W2r = (const float*)d_in[10];
  const float* a2l = (const float*)d_in[11];
  const float* a2r = (const float*)d_in[12];
  const float* b2  = (const float*)d_in[13];
  const int M = in_sizes[0] / DIN;   // 50000
  const int E = in_sizes[1] / 2;     // 500000
  (void)n_in; (void)out_size; (void)ws_size;

  char* w = (char*)d_ws;
  size_t off = 0;
  auto alloc = [&](size_t bytes) -> void* {
    void* p = w + off;
    off += (bytes + 255) & ~(size_t)255;
    return p;
  };
  float* xl1     = (float*)alloc((size_t)M * HID * 4);
  float* el1     = (float*)alloc((size_t)M * 4);
  float* er1     = (float*)alloc((size_t)M * 4);
  float* ms0     = (float*)alloc((size_t)M * DOUT * 4);
  float* out1    = (float*)alloc((size_t)M * HID * 4);
  float* xl2     = (float*)alloc((size_t)M * DOUT * 4);
  float* el2     = (float*)alloc((size_t)M * 4);
  float* er2     = (float*)alloc((size_t)M * 4);
  float* out2    = (float*)alloc((size_t)M * DOUT * 4);
  float* partial = (float*)alloc((size_t)NBLK_COL * 20 * 4);
  float* colsum  = (float*)alloc(32 * 4);
  float* vr1     = (float*)alloc(DIN * 4);
  float* vr2     = (float*)alloc(HID * 4);
  int*   deg     = (int*)alloc((size_t)M * 4);
  int*   rowptr  = (int*)alloc((size_t)(M + 1) * 4);
  int*   cursor  = (int*)alloc((size_t)M * 4);
  int*   csr_src = (int*)alloc((size_t)E * 4);

  hipMemsetAsync(deg, 0, (size_t)M * 4, stream);

  k_prep<<<1, 256, 0, stream>>>(W1r, a1r, W2r, a2r, vr1, vr2);
  k_hist<<<1024, 256, 0, stream>>>(ei, deg, E);
  k_scan<<<1, 1024, 0, stream>>>(deg, rowptr, cursor, M);
  k_csr<<<1024, 256, 0, stream>>>(ei, cursor, csr_src, E);

  k_gemm1<<<(M + 63) / 64, 256, 0, stream>>>(x, W1l, a1l, xl1, el1, M);
  k_node1<<<(M + 7) / 8, 256, 0, stream>>>(x, W0, b0, vr1, ms0, er1, M);

  k_gath1<<<(M + 3) / 4, 256, 0, stream>>>(rowptr, csr_src, el1, er1, xl1, out1, M);
  k_node2<<<(M + 7) / 8, 256, 0, stream>>>(out1, b1, W2l, a2l, vr2, xl2, el2, er2, M);
  k_gath2<<<(M + 7) / 8, 256, 0, stream>>>(rowptr, csr_src, el2, er2, xl2, out2, M);

  k_colsum1<<<NBLK_COL, 256, 0, stream>>>(ms0, partial, M);
  k_colsum2<<<1, 64, 0, stream>>>(partial, colsum);
  k_final<<<(M + 255) / 256, 256, 0, stream>>>(ms0, out2, b2, colsum, (float*)d_out, M);
}

// Round 5
// 551.823 us; speedup vs baseline: 2.1345x; 1.1522x over previous
//
#include <hip/hip_runtime.h>
#include <math.h>

#define DIN 512
#define HID 128
#define DOUT 20
#define NCAT 160          // 128 xl1 | 20 ms0 | 1 er1 | 11 pad
#define BKP 40            // LDS row stride in ushorts (BK=32 + 8 pad)
#define NBLK_COL 200

typedef unsigned int u32;
typedef unsigned short u16;
using short8 = __attribute__((ext_vector_type(8))) short;
using f32x4  = __attribute__((ext_vector_type(4))) float;

__device__ __forceinline__ u16 f2bf(float f) {   // RNE float->bf16
  u32 u = __float_as_uint(f);
  u += 0x7FFFu + ((u >> 16) & 1u);
  return (u16)(u >> 16);
}
__device__ __forceinline__ float bf2f(u16 h) {
  return __uint_as_float(((u32)h) << 16);
}

// ---------- prep: vr1 = W1r^T @ a1r  (512), vr2 = W2r^T @ a2r (128) ----------
__global__ void k_prep(const float* __restrict__ W1r, const float* __restrict__ a1r,
                       const float* __restrict__ W2r, const float* __restrict__ a2r,
                       float* __restrict__ vr1, float* __restrict__ vr2) {
  int t = threadIdx.x;
  for (int k = t; k < DIN; k += 256) {
    float s = 0.f;
    for (int c = 0; c < HID; ++c) s = fmaf(a1r[c], W1r[c * DIN + k], s);
    vr1[k] = s;
  }
  if (t < HID) {
    float s = 0.f;
    for (int c = 0; c < DOUT; ++c) s = fmaf(a2r[c], W2r[c * HID + t], s);
    vr2[t] = s;
  }
}

// ---------- build Wcat = [W1l; W0; vr1; pad] as bf16 hi/lo [160][512] ----------
__global__ void k_prepw(const float* __restrict__ W1l, const float* __restrict__ W0,
                        const float* __restrict__ vr1, u16* __restrict__ whcat,
                        u16* __restrict__ wlcat) {
  int idx = blockIdx.x * 256 + threadIdx.x;     // 160*512 = 81920
  if (idx >= NCAT * DIN) return;
  int c = idx >> 9, k = idx & 511;
  float w = 0.f;
  if (c < HID) w = W1l[c * DIN + k];
  else if (c < HID + DOUT) w = W0[(c - HID) * DIN + k];
  else if (c == HID + DOUT) w = vr1[k];
  u16 h = f2bf(w);
  whcat[idx] = h;
  wlcat[idx] = f2bf(w - bf2f(h));
}

// ---------- CSR build ----------
__global__ void k_hist(const int* __restrict__ ei, int* __restrict__ deg, int E) {
  int stride = gridDim.x * blockDim.x;
  for (int e = blockIdx.x * blockDim.x + threadIdx.x; e < E; e += stride)
    atomicAdd(deg + ei[E + e], 1);
}

__launch_bounds__(1024)
__global__ void k_scan(const int* __restrict__ deg, int* __restrict__ rowptr,
                       int* __restrict__ cursor, int M) {
  __shared__ int part[1024];
  int t = threadIdx.x;
  int chunk = (M + 1023) >> 10;
  int lo = t * chunk, hi = min(lo + chunk, M);
  int s = 0;
  for (int i = lo; i < hi; ++i) s += deg[i];
  part[t] = s;
  __syncthreads();
  for (int off = 1; off < 1024; off <<= 1) {
    int v = (t >= off) ? part[t - off] : 0;
    __syncthreads();
    part[t] += v;
    __syncthreads();
  }
  int run = (t == 0) ? 0 : part[t - 1];
  for (int i = lo; i < hi; ++i) {
    rowptr[i] = run; cursor[i] = run;
    run += deg[i];
  }
  if (t == 1023) rowptr[M] = run;
}

__global__ void k_csr(const int* __restrict__ ei, int* __restrict__ cursor,
                      int* __restrict__ csr_src, int E) {
  int stride = gridDim.x * blockDim.x;
  for (int e = blockIdx.x * blockDim.x + threadIdx.x; e < E; e += stride) {
    int d = ei[E + e];
    int p = atomicAdd(cursor + d, 1);
    csr_src[p] = ei[e];
  }
}

// ---------- fused MFMA GEMM: [xl1 | ms0 | er1] = x @ Wcat^T (bf16 hi/lo split) ----------
// 128x160 tile, BK=32, 4 waves (2 row-halves x 2 col-halves), mfma_f32_16x16x32_bf16.
__launch_bounds__(256, 2)
__global__ void k_fused1(const float* __restrict__ x, const u16* __restrict__ whcat,
                         const u16* __restrict__ wlcat, const float* __restrict__ b0,
                         float* __restrict__ xl1, float* __restrict__ ms0,
                         float* __restrict__ er1, int M) {
  __shared__ u16 xh_s[128 * BKP];
  __shared__ u16 xl_s[128 * BKP];
  __shared__ u16 wh_s[NCAT * BKP];
  __shared__ u16 wl_s[NCAT * BKP];
  const int tid  = threadIdx.x;
  const int wid  = tid >> 6;
  const int wr   = wid >> 1;          // row half: 0..1 (64 rows each)
  const int wc   = wid & 1;           // col half: 0..1 (80 cols each)
  const int lane = tid & 63;
  const int r    = lane & 15;
  const int g    = lane >> 4;
  const int brow = blockIdx.x * 128;

  f32x4 acc[4][5];
#pragma unroll
  for (int mr = 0; mr < 4; ++mr)
#pragma unroll
    for (int nf = 0; nf < 5; ++nf)
      acc[mr][nf] = (f32x4){0.f, 0.f, 0.f, 0.f};

  for (int kt = 0; kt < DIN / 32; ++kt) {
    const int k0 = kt * 32;
    __syncthreads();
    // stage x tile: 128 rows x 8 float4 = 1024 slots, convert fp32 -> bf16 hi/lo
#pragma unroll
    for (int i = 0; i < 4; ++i) {
      int s = i * 256 + tid;
      int row = s >> 3, c4 = s & 7;
      int grow = brow + row;
      float4 v = make_float4(0.f, 0.f, 0.f, 0.f);
      if (grow < M) v = *(const float4*)(x + (size_t)grow * DIN + k0 + c4 * 4);
      u16 h0 = f2bf(v.x), h1 = f2bf(v.y), h2 = f2bf(v.z), h3 = f2bf(v.w);
      *(ushort4*)&xh_s[row * BKP + c4 * 4] = make_ushort4(h0, h1, h2, h3);
      *(ushort4*)&xl_s[row * BKP + c4 * 4] =
          make_ushort4(f2bf(v.x - bf2f(h0)), f2bf(v.y - bf2f(h1)),
                       f2bf(v.z - bf2f(h2)), f2bf(v.w - bf2f(h3)));
    }
    // stage W tiles: 160 rows x 8 ushort4 = 1280 slots each
#pragma unroll
    for (int i = 0; i < 5; ++i) {
      int s = i * 256 + tid;
      int row = s >> 3, c4 = s & 7;
      *(ushort4*)&wh_s[row * BKP + c4 * 4] =
          *(const ushort4*)(whcat + (size_t)row * DIN + k0 + c4 * 4);
      *(ushort4*)&wl_s[row * BKP + c4 * 4] =
          *(const ushort4*)(wlcat + (size_t)row * DIN + k0 + c4 * 4);
    }
    __syncthreads();

    short8 ah[4], alo[4], bh[5], blo[5];
#pragma unroll
    for (int mr = 0; mr < 4; ++mr) {
      int row = wr * 64 + mr * 16 + r;
      ah[mr]  = *(const short8*)&xh_s[row * BKP + g * 8];
      alo[mr] = *(const short8*)&xl_s[row * BKP + g * 8];
    }
#pragma unroll
    for (int nf = 0; nf < 5; ++nf) {
      int col = wc * 80 + nf * 16 + r;
      bh[nf]  = *(const short8*)&wh_s[col * BKP + g * 8];
      blo[nf] = *(const short8*)&wl_s[col * BKP + g * 8];
    }
#pragma unroll
    for (int mr = 0; mr < 4; ++mr)
#pragma unroll
      for (int nf = 0; nf < 5; ++nf) {
        acc[mr][nf] = __builtin_amdgcn_mfma_f32_16x16x32_bf16(ah[mr],  bh[nf],  acc[mr][nf], 0, 0, 0);
        acc[mr][nf] = __builtin_amdgcn_mfma_f32_16x16x32_bf16(ah[mr],  blo[nf], acc[mr][nf], 0, 0, 0);
        acc[mr][nf] = __builtin_amdgcn_mfma_f32_16x16x32_bf16(alo[mr], bh[nf],  acc[mr][nf], 0, 0, 0);
      }
  }

  // epilogue: C[row=(g*4+q)+16*mr+64*wr][col=r+16*nf+80*wc]
#pragma unroll
  for (int mr = 0; mr < 4; ++mr) {
    int growb = brow + wr * 64 + mr * 16 + g * 4;
#pragma unroll
    for (int nf = 0; nf < 5; ++nf) {
      int gcol = wc * 80 + nf * 16 + r;
#pragma unroll
      for (int q = 0; q < 4; ++q) {
        int grow = growb + q;
        if (grow < M) {
          float v = acc[mr][nf][q];
          if (gcol < HID) xl1[(size_t)grow * HID + gcol] = v;
          else if (gcol < HID + DOUT) ms0[(size_t)grow * DOUT + (gcol - HID)] = v + b0[gcol - HID];
          else if (gcol == HID + DOUT) er1[grow] = v;
        }
      }
    }
  }
}

// ---------- el1 = xl1 @ a1l (one 64-lane wave per node) ----------
__launch_bounds__(256)
__global__ void k_el1(const float* __restrict__ xl1, const float* __restrict__ a1l,
                      float* __restrict__ el1, int M) {
  int wv = threadIdx.x >> 6, lane = threadIdx.x & 63;
  int node = blockIdx.x * 4 + wv;
  if (node >= M) return;
  float2 v = *(const float2*)(xl1 + (size_t)node * HID + lane * 2);
  float2 a = *(const float2*)(a1l + lane * 2);
  float s = fmaf(v.y, a.y, v.x * a.x);
#pragma unroll
  for (int m = 1; m < 64; m <<= 1) s += __shfl_xor(s, m);
  if (lane == 0) el1[node] = s;
}

// ---------- gather layer 1: 64 lanes per dst node, 2 cols per lane ----------
__launch_bounds__(256)
__global__ void k_gath1(const int* __restrict__ rowptr, const int* __restrict__ csr_src,
                        const float* __restrict__ el, const float* __restrict__ er,
                        const float* __restrict__ xl1, float* __restrict__ out1, int M) {
  int g = threadIdx.x >> 6, lane = threadIdx.x & 63;
  int d = blockIdx.x * 4 + g;
  if (d >= M) return;
  int lo = rowptr[d], hi = rowptr[d + 1];
  float erd = er[d];
  float a0 = 0.f, a1 = 0.f, wsum = 0.f;
  for (int j = lo; j < hi; ++j) {
    int s = csr_src[j];
    float v = el[s] + erd;
    v = v >= 0.f ? v : 0.2f * v;
    float w = expf(v);
    wsum += w;
    float2 xv = *(const float2*)(xl1 + (size_t)s * HID + lane * 2);
    a0 = fmaf(w, xv.x, a0);
    a1 = fmaf(w, xv.y, a1);
  }
  float inv = 1.f / (wsum + 1e-16f);
  *(float2*)(out1 + (size_t)d * HID + lane * 2) = make_float2(a0 * inv, a1 * inv);
}

// ---------- per-node layer 2 ----------
__launch_bounds__(256)
__global__ void k_node2(const float* __restrict__ out1, const float* __restrict__ b1,
                        const float* __restrict__ W2l, const float* __restrict__ a2l,
                        const float* __restrict__ vr2, float* __restrict__ xl2,
                        float* __restrict__ el2, float* __restrict__ er2, int M) {
  int g = threadIdx.x >> 5, lane = threadIdx.x & 31;
  int node = blockIdx.x * 8 + g;
  if (node >= M) return;
  float4 v = *(const float4*)(out1 + (size_t)node * HID + lane * 4);
  float4 bb = *(const float4*)(b1 + lane * 4);
  float h[4] = {v.x + bb.x, v.y + bb.y, v.z + bb.z, v.w + bb.w};
#pragma unroll
  for (int t = 0; t < 4; ++t) h[t] = h[t] > 0.f ? h[t] : expm1f(h[t]);
  float s[21];
#pragma unroll
  for (int j = 0; j < 21; ++j) {
    const float* wr = (j < 20) ? (W2l + (size_t)j * HID) : vr2;
    float4 wv = *(const float4*)(wr + lane * 4);
    float acc;
    acc = fmaf(h[0], wv.x, 0.f);
    acc = fmaf(h[1], wv.y, acc);
    acc = fmaf(h[2], wv.z, acc);
    acc = fmaf(h[3], wv.w, acc);
#pragma unroll
    for (int m = 1; m < 32; m <<= 1) acc += __shfl_xor(acc, m);
    s[j] = acc;
  }
  if (lane == 0) {
    float el = 0.f;
#pragma unroll
    for (int j = 0; j < 20; ++j) {
      xl2[(size_t)node * DOUT + j] = s[j];
      el = fmaf(s[j], a2l[j], el);
    }
    el2[node] = el;
    er2[node] = s[20];
  }
}

// ---------- gather layer 2 ----------
__launch_bounds__(256)
__global__ void k_gath2(const int* __restrict__ rowptr, const int* __restrict__ csr_src,
                        const float* __restrict__ el, const float* __restrict__ er,
                        const float* __restrict__ xl2, float* __restrict__ out2, int M) {
  int g = threadIdx.x >> 5, lane = threadIdx.x & 31;
  int d = blockIdx.x * 8 + g;
  if (d >= M) return;
  int lo = rowptr[d], hi = rowptr[d + 1];
  float erd = er[d];
  float acc = 0.f, wsum = 0.f;
  for (int j = lo; j < hi; ++j) {
    int s = csr_src[j];
    float v = el[s] + erd;
    v = v >= 0.f ? v : 0.2f * v;
    float w = expf(v);
    wsum += w;
    if (lane < DOUT) acc = fmaf(w, xl2[(size_t)s * DOUT + lane], acc);
  }
  if (lane < DOUT) out2[(size_t)d * DOUT + lane] = acc / (wsum + 1e-16f);
}

// ---------- column sum of exp(ms0) ----------
__launch_bounds__(256)
__global__ void k_colsum1(const float* __restrict__ ms0, float* __restrict__ partial, int M) {
  __shared__ float lds[4][20];
  float sm[20];
#pragma unroll
  for (int j = 0; j < 20; ++j) sm[j] = 0.f;
  int stride = gridDim.x * blockDim.x;
  for (int i = blockIdx.x * blockDim.x + threadIdx.x; i < M; i += stride) {
    const float4* row = (const float4*)(ms0 + (size_t)i * DOUT);
#pragma unroll
    for (int q = 0; q < 5; ++q) {
      float4 v = row[q];
      sm[q * 4 + 0] += expf(v.x);
      sm[q * 4 + 1] += expf(v.y);
      sm[q * 4 + 2] += expf(v.z);
      sm[q * 4 + 3] += expf(v.w);
    }
  }
#pragma unroll
  for (int j = 0; j < 20; ++j) {
#pragma unroll
    for (int k = 1; k < 64; k <<= 1) sm[j] += __shfl_xor(sm[j], k);
  }
  int wave = threadIdx.x >> 6, lane = threadIdx.x & 63;
  if (lane == 0) {
#pragma unroll
    for (int j = 0; j < 20; ++j) lds[wave][j] = sm[j];
  }
  __syncthreads();
  if (threadIdx.x < 20)
    partial[blockIdx.x * 20 + threadIdx.x] =
        lds[0][threadIdx.x] + lds[1][threadIdx.x] + lds[2][threadIdx.x] + lds[3][threadIdx.x];
}

__global__ void k_colsum2(const float* __restrict__ partial, float* __restrict__ colsum) {
  int j = threadIdx.x;
  if (j < 20) {
    float s = 0.f;
    for (int b = 0; b < NBLK_COL; ++b) s += partial[b * 20 + j];
    colsum[j] = s;
  }
}

// ---------- final ----------
__launch_bounds__(256)
__global__ void k_final(const float* __restrict__ ms0, const float* __restrict__ out2,
                        const float* __restrict__ b2, const float* __restrict__ colsum,
                        float* __restrict__ out, int M) {
  int i = blockIdx.x * 256 + threadIdx.x;
  if (i >= M) return;
  float ms1[20];
  const float4* r2 = (const float4*)(out2 + (size_t)i * DOUT);
#pragma unroll
  for (int q = 0; q < 5; ++q) {
    float4 v = r2[q];
    ms1[q * 4 + 0] = v.x + b2[q * 4 + 0];
    ms1[q * 4 + 1] = v.y + b2[q * 4 + 1];
    ms1[q * 4 + 2] = v.z + b2[q * 4 + 2];
    ms1[q * 4 + 3] = v.w + b2[q * 4 + 3];
  }
  float rmax = -INFINITY;
#pragma unroll
  for (int j = 0; j < 20; ++j) rmax = fmaxf(rmax, ms1[j]);
  float rsum = 0.f;
#pragma unroll
  for (int j = 0; j < 20; ++j) { ms1[j] = expf(ms1[j] - rmax); rsum += ms1[j]; }
  const float4* r0 = (const float4*)(ms0 + (size_t)i * DOUT);
  float o[20];
#pragma unroll
  for (int q = 0; q < 5; ++q) {
    float4 v = r0[q];
    o[q * 4 + 0] = expf(v.x) / colsum[q * 4 + 0] * (ms1[q * 4 + 0] / rsum);
    o[q * 4 + 1] = expf(v.y) / colsum[q * 4 + 1] * (ms1[q * 4 + 1] / rsum);
    o[q * 4 + 2] = expf(v.z) / colsum[q * 4 + 2] * (ms1[q * 4 + 2] / rsum);
    o[q * 4 + 3] = expf(v.w) / colsum[q * 4 + 3] * (ms1[q * 4 + 3] / rsum);
  }
  float4* po = (float4*)(out + (size_t)i * DOUT);
#pragma unroll
  for (int q = 0; q < 5; ++q)
    po[q] = make_float4(o[q * 4 + 0], o[q * 4 + 1], o[q * 4 + 2], o[q * 4 + 3]);
}

extern "C" void kernel_launch(void* const* d_in, const int* in_sizes, int n_in,
                              void* d_out, int out_size, void* d_ws, size_t ws_size,
                              hipStream_t stream) {
  const float* x   = (const float*)d_in[0];
  const int*   ei  = (const int*)d_in[1];
  const float* W0  = (const float*)d_in[2];
  const float* b0  = (const float*)d_in[3];
  const float* W1l = (const float*)d_in[4];
  const float* W1r = (const float*)d_in[5];
  const float* a1l = (const float*)d_in[6];
  const float* a1r = (const float*)d_in[7];
  const float* b1  = (const float*)d_in[8];
  const float* W2l = (const float*)d_in[9];
  const float* W2r = (const float*)d_in[10];
  const float* a2l = (const float*)d_in[11];
  const float* a2r = (const float*)d_in[12];
  const float* b2  = (const float*)d_in[13];
  const int M = in_sizes[0] / DIN;   // 50000
  const int E = in_sizes[1] / 2;     // 500000
  (void)n_in; (void)out_size; (void)ws_size;

  char* w = (char*)d_ws;
  size_t off = 0;
  auto alloc = [&](size_t bytes) -> void* {
    void* p = w + off;
    off += (bytes + 255) & ~(size_t)255;
    return p;
  };
  float* xl1     = (float*)alloc((size_t)M * HID * 4);
  float* el1     = (float*)alloc((size_t)M * 4);
  float* er1     = (float*)alloc((size_t)M * 4);
  float* ms0     = (float*)alloc((size_t)M * DOUT * 4);
  float* out1    = (float*)alloc((size_t)M * HID * 4);
  float* xl2     = (float*)alloc((size_t)M * DOUT * 4);
  float* el2     = (float*)alloc((size_t)M * 4);
  float* er2     = (float*)alloc((size_t)M * 4);
  float* out2    = (float*)alloc((size_t)M * DOUT * 4);
  float* partial = (float*)alloc((size_t)NBLK_COL * 20 * 4);
  float* colsum  = (float*)alloc(32 * 4);
  float* vr1     = (float*)alloc(DIN * 4);
  float* vr2     = (float*)alloc(HID * 4);
  u16*   whcat   = (u16*)alloc((size_t)NCAT * DIN * 2);
  u16*   wlcat   = (u16*)alloc((size_t)NCAT * DIN * 2);
  int*   deg     = (int*)alloc((size_t)M * 4);
  int*   rowptr  = (int*)alloc((size_t)(M + 1) * 4);
  int*   cursor  = (int*)alloc((size_t)M * 4);
  int*   csr_src = (int*)alloc((size_t)E * 4);

  hipMemsetAsync(deg, 0, (size_t)M * 4, stream);

  k_prep<<<1, 256, 0, stream>>>(W1r, a1r, W2r, a2r, vr1, vr2);
  k_prepw<<<(NCAT * DIN + 255) / 256, 256, 0, stream>>>(W1l, W0, vr1, whcat, wlcat);
  k_hist<<<1024, 256, 0, stream>>>(ei, deg, E);
  k_scan<<<1, 1024, 0, stream>>>(deg, rowptr, cursor, M);
  k_csr<<<1024, 256, 0, stream>>>(ei, cursor, csr_src, E);

  k_fused1<<<(M + 127) / 128, 256, 0, stream>>>(x, whcat, wlcat, b0, xl1, ms0, er1, M);
  k_el1<<<(M + 3) / 4, 256, 0, stream>>>(xl1, a1l, el1, M);

  k_gath1<<<(M + 3) / 4, 256, 0, stream>>>(rowptr, csr_src, el1, er1, xl1, out1, M);
  k_node2<<<(M + 7) / 8, 256, 0, stream>>>(out1, b1, W2l, a2l, vr2, xl2, el2, er2, M);
  k_gath2<<<(M + 7) / 8, 256, 0, stream>>>(rowptr, csr_src, el2, er2, xl2, out2, M);

  k_colsum1<<<NBLK_COL, 256, 0, stream>>>(ms0, partial, M);
  k_colsum2<<<1, 64, 0, stream>>>(partial, colsum);
  k_final<<<(M + 255) / 256, 256, 0, stream>>>(ms0, out2, b2, colsum, (float*)d_out, M);
}

// Round 6
// 453.488 us; speedup vs baseline: 2.5973x; 1.2168x over previous
//
#include <hip/hip_runtime.h>
#include <math.h>

#define DIN 512
#define HID 128
#define DOUT 20
#define NCAT 160          // 128 xl1 | 20 ms0 | 1 er1 | 11 pad
#define BKP 40            // LDS row stride in ushorts (BK=32 + 8 pad)
#define NBLK_COL 200
#define SCAN_TILE 1024

typedef unsigned int u32;
typedef unsigned short u16;
using short8 = __attribute__((ext_vector_type(8))) short;
using f32x4  = __attribute__((ext_vector_type(4))) float;

__device__ __forceinline__ u16 f2bf(float f) {   // RNE float->bf16
  u32 u = __float_as_uint(f);
  u += 0x7FFFu + ((u >> 16) & 1u);
  return (u16)(u >> 16);
}
__device__ __forceinline__ float bf2f(u16 h) {
  return __uint_as_float(((u32)h) << 16);
}

// ---------- prep: vr1 = W1r^T @ a1r  (512), vr2 = W2r^T @ a2r (128) ----------
__global__ void k_prep(const float* __restrict__ W1r, const float* __restrict__ a1r,
                       const float* __restrict__ W2r, const float* __restrict__ a2r,
                       float* __restrict__ vr1, float* __restrict__ vr2) {
  int t = threadIdx.x;
  for (int k = t; k < DIN; k += 256) {
    float s = 0.f;
    for (int c = 0; c < HID; ++c) s = fmaf(a1r[c], W1r[c * DIN + k], s);
    vr1[k] = s;
  }
  if (t < HID) {
    float s = 0.f;
    for (int c = 0; c < DOUT; ++c) s = fmaf(a2r[c], W2r[c * HID + t], s);
    vr2[t] = s;
  }
}

// ---------- build Wcat = [W1l; W0; vr1; pad] as bf16 hi/lo [160][512] ----------
__global__ void k_prepw(const float* __restrict__ W1l, const float* __restrict__ W0,
                        const float* __restrict__ vr1, u16* __restrict__ whcat,
                        u16* __restrict__ wlcat) {
  int idx = blockIdx.x * 256 + threadIdx.x;     // 160*512 = 81920
  if (idx >= NCAT * DIN) return;
  int c = idx >> 9, k = idx & 511;
  float w = 0.f;
  if (c < HID) w = W1l[c * DIN + k];
  else if (c < HID + DOUT) w = W0[(c - HID) * DIN + k];
  else if (c == HID + DOUT) w = vr1[k];
  u16 h = f2bf(w);
  whcat[idx] = h;
  wlcat[idx] = f2bf(w - bf2f(h));
}

// ---------- CSR build: histogram ----------
__global__ void k_hist(const int* __restrict__ ei, int* __restrict__ deg, int E) {
  int stride = gridDim.x * blockDim.x;
  for (int e = blockIdx.x * blockDim.x + threadIdx.x; e < E; e += stride)
    atomicAdd(deg + ei[E + e], 1);
}

// ---------- parallel scan phase 1: per-tile (1024 elems) sums ----------
__launch_bounds__(256)
__global__ void k_scan1(const int* __restrict__ deg, int* __restrict__ tilesum, int M) {
  __shared__ int ws[4];
  int t = threadIdx.x;
  int idx = blockIdx.x * SCAN_TILE + t * 4;
  int4 d = make_int4(0, 0, 0, 0);
  if (idx + 3 < M) d = *(const int4*)(deg + idx);
  else {
    if (idx + 0 < M) d.x = deg[idx + 0];
    if (idx + 1 < M) d.y = deg[idx + 1];
    if (idx + 2 < M) d.z = deg[idx + 2];
    if (idx + 3 < M) d.w = deg[idx + 3];
  }
  int s = d.x + d.y + d.z + d.w;
#pragma unroll
  for (int m = 1; m < 64; m <<= 1) s += __shfl_xor(s, m);
  int lane = t & 63, wave = t >> 6;
  if (lane == 0) ws[wave] = s;
  __syncthreads();
  if (t == 0) tilesum[blockIdx.x] = ws[0] + ws[1] + ws[2] + ws[3];
}

// ---------- scan phase 2: one wave scans <=64 tile sums; writes rowptr[M] ----------
__global__ void k_scan2(const int* __restrict__ tilesum, int* __restrict__ tileoff,
                        int* __restrict__ rowptr, int nb, int M) {
  int t = threadIdx.x;                 // 64 threads
  int own = (t < nb) ? tilesum[t] : 0;
  int v = own;
#pragma unroll
  for (int off = 1; off < 64; off <<= 1) {
    int u = __shfl_up(v, off);
    if (t >= off) v += u;
  }
  if (t < nb) tileoff[t] = v - own;    // exclusive
  if (t == nb - 1) rowptr[M] = v;      // total edge count
}

// ---------- scan phase 3: per-tile block scan + tile offset ----------
__launch_bounds__(256)
__global__ void k_scan3(const int* __restrict__ deg, const int* __restrict__ tileoff,
                        int* __restrict__ rowptr, int* __restrict__ cursor, int M) {
  __shared__ int wsums[4];
  int t = threadIdx.x;
  int idx = blockIdx.x * SCAN_TILE + t * 4;
  int4 d = make_int4(0, 0, 0, 0);
  if (idx + 3 < M) d = *(const int4*)(deg + idx);
  else {
    if (idx + 0 < M) d.x = deg[idx + 0];
    if (idx + 1 < M) d.y = deg[idx + 1];
    if (idx + 2 < M) d.z = deg[idx + 2];
    if (idx + 3 < M) d.w = deg[idx + 3];
  }
  int s0 = d.x, s01 = d.x + d.y, s012 = s01 + d.z, tsum = s012 + d.w;
  int lane = t & 63, wave = t >> 6;
  int v = tsum;
#pragma unroll
  for (int off = 1; off < 64; off <<= 1) {
    int u = __shfl_up(v, off);
    if (lane >= off) v += u;
  }
  if (lane == 63) wsums[wave] = v;
  __syncthreads();
  int woff = 0;
  for (int i = 0; i < wave; ++i) woff += wsums[i];
  int ex = tileoff[blockIdx.x] + woff + (v - tsum);
  if (idx + 0 < M) { rowptr[idx + 0] = ex;        cursor[idx + 0] = ex; }
  if (idx + 1 < M) { rowptr[idx + 1] = ex + s0;   cursor[idx + 1] = ex + s0; }
  if (idx + 2 < M) { rowptr[idx + 2] = ex + s01;  cursor[idx + 2] = ex + s01; }
  if (idx + 3 < M) { rowptr[idx + 3] = ex + s012; cursor[idx + 3] = ex + s012; }
}

// ---------- CSR build: bucket srcs by dst ----------
__global__ void k_csr(const int* __restrict__ ei, int* __restrict__ cursor,
                      int* __restrict__ csr_src, int E) {
  int stride = gridDim.x * blockDim.x;
  for (int e = blockIdx.x * blockDim.x + threadIdx.x; e < E; e += stride) {
    int d = ei[E + e];
    int p = atomicAdd(cursor + d, 1);
    csr_src[p] = ei[e];
  }
}

// ---------- fused MFMA GEMM: [xl1 | ms0 | er1] = x @ Wcat^T (bf16 hi/lo split) ----------
__launch_bounds__(256, 2)
__global__ void k_fused1(const float* __restrict__ x, const u16* __restrict__ whcat,
                         const u16* __restrict__ wlcat, const float* __restrict__ b0,
                         float* __restrict__ xl1, float* __restrict__ ms0,
                         float* __restrict__ er1, int M) {
  __shared__ u16 xh_s[128 * BKP];
  __shared__ u16 xl_s[128 * BKP];
  __shared__ u16 wh_s[NCAT * BKP];
  __shared__ u16 wl_s[NCAT * BKP];
  const int tid  = threadIdx.x;
  const int wid  = tid >> 6;
  const int wr   = wid >> 1;
  const int wc   = wid & 1;
  const int lane = tid & 63;
  const int r    = lane & 15;
  const int g    = lane >> 4;
  const int brow = blockIdx.x * 128;

  f32x4 acc[4][5];
#pragma unroll
  for (int mr = 0; mr < 4; ++mr)
#pragma unroll
    for (int nf = 0; nf < 5; ++nf)
      acc[mr][nf] = (f32x4){0.f, 0.f, 0.f, 0.f};

  for (int kt = 0; kt < DIN / 32; ++kt) {
    const int k0 = kt * 32;
    __syncthreads();
#pragma unroll
    for (int i = 0; i < 4; ++i) {
      int s = i * 256 + tid;
      int row = s >> 3, c4 = s & 7;
      int grow = brow + row;
      float4 v = make_float4(0.f, 0.f, 0.f, 0.f);
      if (grow < M) v = *(const float4*)(x + (size_t)grow * DIN + k0 + c4 * 4);
      u16 h0 = f2bf(v.x), h1 = f2bf(v.y), h2 = f2bf(v.z), h3 = f2bf(v.w);
      *(ushort4*)&xh_s[row * BKP + c4 * 4] = make_ushort4(h0, h1, h2, h3);
      *(ushort4*)&xl_s[row * BKP + c4 * 4] =
          make_ushort4(f2bf(v.x - bf2f(h0)), f2bf(v.y - bf2f(h1)),
                       f2bf(v.z - bf2f(h2)), f2bf(v.w - bf2f(h3)));
    }
#pragma unroll
    for (int i = 0; i < 5; ++i) {
      int s = i * 256 + tid;
      int row = s >> 3, c4 = s & 7;
      *(ushort4*)&wh_s[row * BKP + c4 * 4] =
          *(const ushort4*)(whcat + (size_t)row * DIN + k0 + c4 * 4);
      *(ushort4*)&wl_s[row * BKP + c4 * 4] =
          *(const ushort4*)(wlcat + (size_t)row * DIN + k0 + c4 * 4);
    }
    __syncthreads();

    short8 ah[4], alo[4], bh[5], blo[5];
#pragma unroll
    for (int mr = 0; mr < 4; ++mr) {
      int row = wr * 64 + mr * 16 + r;
      ah[mr]  = *(const short8*)&xh_s[row * BKP + g * 8];
      alo[mr] = *(const short8*)&xl_s[row * BKP + g * 8];
    }
#pragma unroll
    for (int nf = 0; nf < 5; ++nf) {
      int col = wc * 80 + nf * 16 + r;
      bh[nf]  = *(const short8*)&wh_s[col * BKP + g * 8];
      blo[nf] = *(const short8*)&wl_s[col * BKP + g * 8];
    }
#pragma unroll
    for (int mr = 0; mr < 4; ++mr)
#pragma unroll
      for (int nf = 0; nf < 5; ++nf) {
        acc[mr][nf] = __builtin_amdgcn_mfma_f32_16x16x32_bf16(ah[mr],  bh[nf],  acc[mr][nf], 0, 0, 0);
        acc[mr][nf] = __builtin_amdgcn_mfma_f32_16x16x32_bf16(ah[mr],  blo[nf], acc[mr][nf], 0, 0, 0);
        acc[mr][nf] = __builtin_amdgcn_mfma_f32_16x16x32_bf16(alo[mr], bh[nf],  acc[mr][nf], 0, 0, 0);
      }
  }

#pragma unroll
  for (int mr = 0; mr < 4; ++mr) {
    int growb = brow + wr * 64 + mr * 16 + g * 4;
#pragma unroll
    for (int nf = 0; nf < 5; ++nf) {
      int gcol = wc * 80 + nf * 16 + r;
#pragma unroll
      for (int q = 0; q < 4; ++q) {
        int grow = growb + q;
        if (grow < M) {
          float v = acc[mr][nf][q];
          if (gcol < HID) xl1[(size_t)grow * HID + gcol] = v;
          else if (gcol < HID + DOUT) ms0[(size_t)grow * DOUT + (gcol - HID)] = v + b0[gcol - HID];
          else if (gcol == HID + DOUT) er1[grow] = v;
        }
      }
    }
  }
}

// ---------- el1 = xl1 @ a1l ----------
__launch_bounds__(256)
__global__ void k_el1(const float* __restrict__ xl1, const float* __restrict__ a1l,
                      float* __restrict__ el1, int M) {
  int wv = threadIdx.x >> 6, lane = threadIdx.x & 63;
  int node = blockIdx.x * 4 + wv;
  if (node >= M) return;
  float2 v = *(const float2*)(xl1 + (size_t)node * HID + lane * 2);
  float2 a = *(const float2*)(a1l + lane * 2);
  float s = fmaf(v.y, a.y, v.x * a.x);
#pragma unroll
  for (int m = 1; m < 64; m <<= 1) s += __shfl_xor(s, m);
  if (lane == 0) el1[node] = s;
}

// ---------- gather layer 1 ----------
__launch_bounds__(256)
__global__ void k_gath1(const int* __restrict__ rowptr, const int* __restrict__ csr_src,
                        const float* __restrict__ el, const float* __restrict__ er,
                        const float* __restrict__ xl1, float* __restrict__ out1, int M) {
  int g = threadIdx.x >> 6, lane = threadIdx.x & 63;
  int d = blockIdx.x * 4 + g;
  if (d >= M) return;
  int lo = rowptr[d], hi = rowptr[d + 1];
  float erd = er[d];
  float a0 = 0.f, a1 = 0.f, wsum = 0.f;
  for (int j = lo; j < hi; ++j) {
    int s = csr_src[j];
    float v = el[s] + erd;
    v = v >= 0.f ? v : 0.2f * v;
    float w = expf(v);
    wsum += w;
    float2 xv = *(const float2*)(xl1 + (size_t)s * HID + lane * 2);
    a0 = fmaf(w, xv.x, a0);
    a1 = fmaf(w, xv.y, a1);
  }
  float inv = 1.f / (wsum + 1e-16f);
  *(float2*)(out1 + (size_t)d * HID + lane * 2) = make_float2(a0 * inv, a1 * inv);
}

// ---------- per-node layer 2 ----------
__launch_bounds__(256)
__global__ void k_node2(const float* __restrict__ out1, const float* __restrict__ b1,
                        const float* __restrict__ W2l, const float* __restrict__ a2l,
                        const float* __restrict__ vr2, float* __restrict__ xl2,
                        float* __restrict__ el2, float* __restrict__ er2, int M) {
  int g = threadIdx.x >> 5, lane = threadIdx.x & 31;
  int node = blockIdx.x * 8 + g;
  if (node >= M) return;
  float4 v = *(const float4*)(out1 + (size_t)node * HID + lane * 4);
  float4 bb = *(const float4*)(b1 + lane * 4);
  float h[4] = {v.x + bb.x, v.y + bb.y, v.z + bb.z, v.w + bb.w};
#pragma unroll
  for (int t = 0; t < 4; ++t) h[t] = h[t] > 0.f ? h[t] : expm1f(h[t]);
  float s[21];
#pragma unroll
  for (int j = 0; j < 21; ++j) {
    const float* wr = (j < 20) ? (W2l + (size_t)j * HID) : vr2;
    float4 wv = *(const float4*)(wr + lane * 4);
    float acc;
    acc = fmaf(h[0], wv.x, 0.f);
    acc = fmaf(h[1], wv.y, acc);
    acc = fmaf(h[2], wv.z, acc);
    acc = fmaf(h[3], wv.w, acc);
#pragma unroll
    for (int m = 1; m < 32; m <<= 1) acc += __shfl_xor(acc, m);
    s[j] = acc;
  }
  if (lane == 0) {
    float el = 0.f;
#pragma unroll
    for (int j = 0; j < 20; ++j) {
      xl2[(size_t)node * DOUT + j] = s[j];
      el = fmaf(s[j], a2l[j], el);
    }
    el2[node] = el;
    er2[node] = s[20];
  }
}

// ---------- gather layer 2 ----------
__launch_bounds__(256)
__global__ void k_gath2(const int* __restrict__ rowptr, const int* __restrict__ csr_src,
                        const float* __restrict__ el, const float* __restrict__ er,
                        const float* __restrict__ xl2, float* __restrict__ out2, int M) {
  int g = threadIdx.x >> 5, lane = threadIdx.x & 31;
  int d = blockIdx.x * 8 + g;
  if (d >= M) return;
  int lo = rowptr[d], hi = rowptr[d + 1];
  float erd = er[d];
  float acc = 0.f, wsum = 0.f;
  for (int j = lo; j < hi; ++j) {
    int s = csr_src[j];
    float v = el[s] + erd;
    v = v >= 0.f ? v : 0.2f * v;
    float w = expf(v);
    wsum += w;
    if (lane < DOUT) acc = fmaf(w, xl2[(size_t)s * DOUT + lane], acc);
  }
  if (lane < DOUT) out2[(size_t)d * DOUT + lane] = acc / (wsum + 1e-16f);
}

// ---------- column sum of exp(ms0) ----------
__launch_bounds__(256)
__global__ void k_colsum1(const float* __restrict__ ms0, float* __restrict__ partial, int M) {
  __shared__ float lds[4][20];
  float sm[20];
#pragma unroll
  for (int j = 0; j < 20; ++j) sm[j] = 0.f;
  int stride = gridDim.x * blockDim.x;
  for (int i = blockIdx.x * blockDim.x + threadIdx.x; i < M; i += stride) {
    const float4* row = (const float4*)(ms0 + (size_t)i * DOUT);
#pragma unroll
    for (int q = 0; q < 5; ++q) {
      float4 v = row[q];
      sm[q * 4 + 0] += expf(v.x);
      sm[q * 4 + 1] += expf(v.y);
      sm[q * 4 + 2] += expf(v.z);
      sm[q * 4 + 3] += expf(v.w);
    }
  }
#pragma unroll
  for (int j = 0; j < 20; ++j) {
#pragma unroll
    for (int k = 1; k < 64; k <<= 1) sm[j] += __shfl_xor(sm[j], k);
  }
  int wave = threadIdx.x >> 6, lane = threadIdx.x & 63;
  if (lane == 0) {
#pragma unroll
    for (int j = 0; j < 20; ++j) lds[wave][j] = sm[j];
  }
  __syncthreads();
  if (threadIdx.x < 20)
    partial[blockIdx.x * 20 + threadIdx.x] =
        lds[0][threadIdx.x] + lds[1][threadIdx.x] + lds[2][threadIdx.x] + lds[3][threadIdx.x];
}

__global__ void k_colsum2(const float* __restrict__ partial, float* __restrict__ colsum) {
  int j = threadIdx.x;
  if (j < 20) {
    float s = 0.f;
    for (int b = 0; b < NBLK_COL; ++b) s += partial[b * 20 + j];
    colsum[j] = s;
  }
}

// ---------- final ----------
__launch_bounds__(256)
__global__ void k_final(const float* __restrict__ ms0, const float* __restrict__ out2,
                        const float* __restrict__ b2, const float* __restrict__ colsum,
                        float* __restrict__ out, int M) {
  int i = blockIdx.x * 256 + threadIdx.x;
  if (i >= M) return;
  float ms1[20];
  const float4* r2 = (const float4*)(out2 + (size_t)i * DOUT);
#pragma unroll
  for (int q = 0; q < 5; ++q) {
    float4 v = r2[q];
    ms1[q * 4 + 0] = v.x + b2[q * 4 + 0];
    ms1[q * 4 + 1] = v.y + b2[q * 4 + 1];
    ms1[q * 4 + 2] = v.z + b2[q * 4 + 2];
    ms1[q * 4 + 3] = v.w + b2[q * 4 + 3];
  }
  float rmax = -INFINITY;
#pragma unroll
  for (int j = 0; j < 20; ++j) rmax = fmaxf(rmax, ms1[j]);
  float rsum = 0.f;
#pragma unroll
  for (int j = 0; j < 20; ++j) { ms1[j] = expf(ms1[j] - rmax); rsum += ms1[j]; }
  const float4* r0 = (const float4*)(ms0 + (size_t)i * DOUT);
  float o[20];
#pragma unroll
  for (int q = 0; q < 5; ++q) {
    float4 v = r0[q];
    o[q * 4 + 0] = expf(v.x) / colsum[q * 4 + 0] * (ms1[q * 4 + 0] / rsum);
    o[q * 4 + 1] = expf(v.y) / colsum[q * 4 + 1] * (ms1[q * 4 + 1] / rsum);
    o[q * 4 + 2] = expf(v.z) / colsum[q * 4 + 2] * (ms1[q * 4 + 2] / rsum);
    o[q * 4 + 3] = expf(v.w) / colsum[q * 4 + 3] * (ms1[q * 4 + 3] / rsum);
  }
  float4* po = (float4*)(out + (size_t)i * DOUT);
#pragma unroll
  for (int q = 0; q < 5; ++q)
    po[q] = make_float4(o[q * 4 + 0], o[q * 4 + 1], o[q * 4 + 2], o[q * 4 + 3]);
}

extern "C" void kernel_launch(void* const* d_in, const int* in_sizes, int n_in,
                              void* d_out, int out_size, void* d_ws, size_t ws_size,
                              hipStream_t stream) {
  const float* x   = (const float*)d_in[0];
  const int*   ei  = (const int*)d_in[1];
  const float* W0  = (const float*)d_in[2];
  const float* b0  = (const float*)d_in[3];
  const float* W1l = (const float*)d_in[4];
  const float* W1r = (const float*)d_in[5];
  const float* a1l = (const float*)d_in[6];
  const float* a1r = (const float*)d_in[7];
  const float* b1  = (const float*)d_in[8];
  const float* W2l = (const float*)d_in[9];
  const float* W2r = (const float*)d_in[10];
  const float* a2l = (const float*)d_in[11];
  const float* a2r = (const float*)d_in[12];
  const float* b2  = (const float*)d_in[13];
  const int M = in_sizes[0] / DIN;   // 50000
  const int E = in_sizes[1] / 2;     // 500000
  const int NB_SCAN = (M + SCAN_TILE - 1) / SCAN_TILE;   // 49 (<=64 required)
  (void)n_in; (void)out_size; (void)ws_size;

  char* w = (char*)d_ws;
  size_t off = 0;
  auto alloc = [&](size_t bytes) -> void* {
    void* p = w + off;
    off += (bytes + 255) & ~(size_t)255;
    return p;
  };
  float* xl1     = (float*)alloc((size_t)M * HID * 4);
  float* el1     = (float*)alloc((size_t)M * 4);
  float* er1     = (float*)alloc((size_t)M * 4);
  float* ms0     = (float*)alloc((size_t)M * DOUT * 4);
  float* out1    = (float*)alloc((size_t)M * HID * 4);
  float* xl2     = (float*)alloc((size_t)M * DOUT * 4);
  float* el2     = (float*)alloc((size_t)M * 4);
  float* er2     = (float*)alloc((size_t)M * 4);
  float* out2    = (float*)alloc((size_t)M * DOUT * 4);
  float* partial = (float*)alloc((size_t)NBLK_COL * 20 * 4);
  float* colsum  = (float*)alloc(32 * 4);
  float* vr1     = (float*)alloc(DIN * 4);
  float* vr2     = (float*)alloc(HID * 4);
  u16*   whcat   = (u16*)alloc((size_t)NCAT * DIN * 2);
  u16*   wlcat   = (u16*)alloc((size_t)NCAT * DIN * 2);
  int*   deg     = (int*)alloc((size_t)M * 4);
  int*   rowptr  = (int*)alloc((size_t)(M + 1) * 4);
  int*   cursor  = (int*)alloc((size_t)M * 4);
  int*   csr_src = (int*)alloc((size_t)E * 4);
  int*   tilesum = (int*)alloc(64 * 4);
  int*   tileoff = (int*)alloc(64 * 4);

  hipMemsetAsync(deg, 0, (size_t)M * 4, stream);

  k_prep<<<1, 256, 0, stream>>>(W1r, a1r, W2r, a2r, vr1, vr2);
  k_prepw<<<(NCAT * DIN + 255) / 256, 256, 0, stream>>>(W1l, W0, vr1, whcat, wlcat);
  k_hist<<<1024, 256, 0, stream>>>(ei, deg, E);
  k_scan1<<<NB_SCAN, 256, 0, stream>>>(deg, tilesum, M);
  k_scan2<<<1, 64, 0, stream>>>(tilesum, tileoff, rowptr, NB_SCAN, M);
  k_scan3<<<NB_SCAN, 256, 0, stream>>>(deg, tileoff, rowptr, cursor, M);
  k_csr<<<1024, 256, 0, stream>>>(ei, cursor, csr_src, E);

  k_fused1<<<(M + 127) / 128, 256, 0, stream>>>(x, whcat, wlcat, b0, xl1, ms0, er1, M);
  k_el1<<<(M + 3) / 4, 256, 0, stream>>>(xl1, a1l, el1, M);

  k_gath1<<<(M + 3) / 4, 256, 0, stream>>>(rowptr, csr_src, el1, er1, xl1, out1, M);
  k_node2<<<(M + 7) / 8, 256, 0, stream>>>(out1, b1, W2l, a2l, vr2, xl2, el2, er2, M);
  k_gath2<<<(M + 7) / 8, 256, 0, stream>>>(rowptr, csr_src, el2, er2, xl2, out2, M);

  k_colsum1<<<NBLK_COL, 256, 0, stream>>>(ms0, partial, M);
  k_colsum2<<<1, 64, 0, stream>>>(partial, colsum);
  k_final<<<(M + 255) / 256, 256, 0, stream>>>(ms0, out2, b2, colsum, (float*)d_out, M);
}

// Round 7
// 438.891 us; speedup vs baseline: 2.6837x; 1.0333x over previous
//
#include <hip/hip_runtime.h>
#include <math.h>

#define DIN 512
#define HID 128
#define DOUT 20
#define NCAT 160          // 128 xl1 | 20 ms0 | 1 er1 | 11 pad
#define BKP 40            // LDS row stride in ushorts (BK=32 + 8 pad)
#define NBLK_COL 200
#define SCAN_TILE 1024

typedef unsigned int u32;
typedef unsigned short u16;
using short8 = __attribute__((ext_vector_type(8))) short;
using f32x4  = __attribute__((ext_vector_type(4))) float;

__device__ __forceinline__ u16 f2bf(float f) {   // RNE float->bf16
  u32 u = __float_as_uint(f);
  u += 0x7FFFu + ((u >> 16) & 1u);
  return (u16)(u >> 16);
}
__device__ __forceinline__ float bf2f(u16 h) {
  return __uint_as_float(((u32)h) << 16);
}

// ---------- prep: vr1 = W1r^T @ a1r  (512), vr2 = W2r^T @ a2r (128) ----------
__global__ void k_prep(const float* __restrict__ W1r, const float* __restrict__ a1r,
                       const float* __restrict__ W2r, const float* __restrict__ a2r,
                       float* __restrict__ vr1, float* __restrict__ vr2) {
  int t = threadIdx.x;
  for (int k = t; k < DIN; k += 256) {
    float s = 0.f;
    for (int c = 0; c < HID; ++c) s = fmaf(a1r[c], W1r[c * DIN + k], s);
    vr1[k] = s;
  }
  if (t < HID) {
    float s = 0.f;
    for (int c = 0; c < DOUT; ++c) s = fmaf(a2r[c], W2r[c * HID + t], s);
    vr2[t] = s;
  }
}

// ---------- build Wcat = [W1l; W0; vr1; pad] as bf16 hi/lo [160][512] ----------
__global__ void k_prepw(const float* __restrict__ W1l, const float* __restrict__ W0,
                        const float* __restrict__ vr1, u16* __restrict__ whcat,
                        u16* __restrict__ wlcat) {
  int idx = blockIdx.x * 256 + threadIdx.x;     // 160*512 = 81920
  if (idx >= NCAT * DIN) return;
  int c = idx >> 9, k = idx & 511;
  float w = 0.f;
  if (c < HID) w = W1l[c * DIN + k];
  else if (c < HID + DOUT) w = W0[(c - HID) * DIN + k];
  else if (c == HID + DOUT) w = vr1[k];
  u16 h = f2bf(w);
  whcat[idx] = h;
  wlcat[idx] = f2bf(w - bf2f(h));
}

// ---------- CSR build: histogram ----------
__global__ void k_hist(const int* __restrict__ ei, int* __restrict__ deg, int E) {
  int stride = gridDim.x * blockDim.x;
  for (int e = blockIdx.x * blockDim.x + threadIdx.x; e < E; e += stride)
    atomicAdd(deg + ei[E + e], 1);
}

// ---------- parallel scan phase 1: per-tile (1024 elems) sums ----------
__launch_bounds__(256)
__global__ void k_scan1(const int* __restrict__ deg, int* __restrict__ tilesum, int M) {
  __shared__ int ws[4];
  int t = threadIdx.x;
  int idx = blockIdx.x * SCAN_TILE + t * 4;
  int4 d = make_int4(0, 0, 0, 0);
  if (idx + 3 < M) d = *(const int4*)(deg + idx);
  else {
    if (idx + 0 < M) d.x = deg[idx + 0];
    if (idx + 1 < M) d.y = deg[idx + 1];
    if (idx + 2 < M) d.z = deg[idx + 2];
    if (idx + 3 < M) d.w = deg[idx + 3];
  }
  int s = d.x + d.y + d.z + d.w;
#pragma unroll
  for (int m = 1; m < 64; m <<= 1) s += __shfl_xor(s, m);
  int lane = t & 63, wave = t >> 6;
  if (lane == 0) ws[wave] = s;
  __syncthreads();
  if (t == 0) tilesum[blockIdx.x] = ws[0] + ws[1] + ws[2] + ws[3];
}

// ---------- scan phase 2: one wave scans <=64 tile sums; writes rowptr[M] ----------
__global__ void k_scan2(const int* __restrict__ tilesum, int* __restrict__ tileoff,
                        int* __restrict__ rowptr, int nb, int M) {
  int t = threadIdx.x;                 // 64 threads
  int own = (t < nb) ? tilesum[t] : 0;
  int v = own;
#pragma unroll
  for (int off = 1; off < 64; off <<= 1) {
    int u = __shfl_up(v, off);
    if (t >= off) v += u;
  }
  if (t < nb) tileoff[t] = v - own;    // exclusive
  if (t == nb - 1) rowptr[M] = v;      // total edge count
}

// ---------- scan phase 3: per-tile block scan + tile offset ----------
__launch_bounds__(256)
__global__ void k_scan3(const int* __restrict__ deg, const int* __restrict__ tileoff,
                        int* __restrict__ rowptr, int* __restrict__ cursor, int M) {
  __shared__ int wsums[4];
  int t = threadIdx.x;
  int idx = blockIdx.x * SCAN_TILE + t * 4;
  int4 d = make_int4(0, 0, 0, 0);
  if (idx + 3 < M) d = *(const int4*)(deg + idx);
  else {
    if (idx + 0 < M) d.x = deg[idx + 0];
    if (idx + 1 < M) d.y = deg[idx + 1];
    if (idx + 2 < M) d.z = deg[idx + 2];
    if (idx + 3 < M) d.w = deg[idx + 3];
  }
  int s0 = d.x, s01 = d.x + d.y, s012 = s01 + d.z, tsum = s012 + d.w;
  int lane = t & 63, wave = t >> 6;
  int v = tsum;
#pragma unroll
  for (int off = 1; off < 64; off <<= 1) {
    int u = __shfl_up(v, off);
    if (lane >= off) v += u;
  }
  if (lane == 63) wsums[wave] = v;
  __syncthreads();
  int woff = 0;
  for (int i = 0; i < wave; ++i) woff += wsums[i];
  int ex = tileoff[blockIdx.x] + woff + (v - tsum);
  if (idx + 0 < M) { rowptr[idx + 0] = ex;        cursor[idx + 0] = ex; }
  if (idx + 1 < M) { rowptr[idx + 1] = ex + s0;   cursor[idx + 1] = ex + s0; }
  if (idx + 2 < M) { rowptr[idx + 2] = ex + s01;  cursor[idx + 2] = ex + s01; }
  if (idx + 3 < M) { rowptr[idx + 3] = ex + s012; cursor[idx + 3] = ex + s012; }
}

// ---------- CSR build: bucket srcs by dst ----------
__global__ void k_csr(const int* __restrict__ ei, int* __restrict__ cursor,
                      int* __restrict__ csr_src, int E) {
  int stride = gridDim.x * blockDim.x;
  for (int e = blockIdx.x * blockDim.x + threadIdx.x; e < E; e += stride) {
    int d = ei[E + e];
    int p = atomicAdd(cursor + d, 1);
    csr_src[p] = ei[e];
  }
}

// ---------- fused MFMA GEMM: [xl1 | ms0 | er1] = x @ Wcat^T (bf16 hi/lo split) ----------
// BM=64 tile (grid 782 -> ~3 blocks/CU), 4 waves (2 row x 2 col), 35.8 KB LDS.
__launch_bounds__(256, 4)
__global__ void k_fused1(const float* __restrict__ x, const u16* __restrict__ whcat,
                         const u16* __restrict__ wlcat, const float* __restrict__ b0,
                         float* __restrict__ xl1, float* __restrict__ ms0,
                         float* __restrict__ er1, int M) {
  __shared__ u16 xh_s[64 * BKP];
  __shared__ u16 xl_s[64 * BKP];
  __shared__ u16 wh_s[NCAT * BKP];
  __shared__ u16 wl_s[NCAT * BKP];
  const int tid  = threadIdx.x;
  const int wid  = tid >> 6;
  const int wr   = wid >> 1;          // row half: 0..1 (32 rows each)
  const int wc   = wid & 1;           // col half: 0..1 (80 cols each)
  const int lane = tid & 63;
  const int r    = lane & 15;
  const int g    = lane >> 4;
  const int brow = blockIdx.x * 64;

  f32x4 acc[2][5];
#pragma unroll
  for (int mr = 0; mr < 2; ++mr)
#pragma unroll
    for (int nf = 0; nf < 5; ++nf)
      acc[mr][nf] = (f32x4){0.f, 0.f, 0.f, 0.f};

  for (int kt = 0; kt < DIN / 32; ++kt) {
    const int k0 = kt * 32;
    __syncthreads();
    // stage x tile: 64 rows x 8 float4 = 512 slots (2/thread), fp32 -> bf16 hi/lo
#pragma unroll
    for (int i = 0; i < 2; ++i) {
      int s = i * 256 + tid;
      int row = s >> 3, c4 = s & 7;
      int grow = brow + row;
      float4 v = make_float4(0.f, 0.f, 0.f, 0.f);
      if (grow < M) v = *(const float4*)(x + (size_t)grow * DIN + k0 + c4 * 4);
      u16 h0 = f2bf(v.x), h1 = f2bf(v.y), h2 = f2bf(v.z), h3 = f2bf(v.w);
      *(ushort4*)&xh_s[row * BKP + c4 * 4] = make_ushort4(h0, h1, h2, h3);
      *(ushort4*)&xl_s[row * BKP + c4 * 4] =
          make_ushort4(f2bf(v.x - bf2f(h0)), f2bf(v.y - bf2f(h1)),
                       f2bf(v.z - bf2f(h2)), f2bf(v.w - bf2f(h3)));
    }
    // stage W tiles: 160 rows x 8 ushort4 = 1280 slots each
#pragma unroll
    for (int i = 0; i < 5; ++i) {
      int s = i * 256 + tid;
      int row = s >> 3, c4 = s & 7;
      *(ushort4*)&wh_s[row * BKP + c4 * 4] =
          *(const ushort4*)(whcat + (size_t)row * DIN + k0 + c4 * 4);
      *(ushort4*)&wl_s[row * BKP + c4 * 4] =
          *(const ushort4*)(wlcat + (size_t)row * DIN + k0 + c4 * 4);
    }
    __syncthreads();

    short8 ah[2], alo[2], bh[5], blo[5];
#pragma unroll
    for (int mr = 0; mr < 2; ++mr) {
      int row = wr * 32 + mr * 16 + r;
      ah[mr]  = *(const short8*)&xh_s[row * BKP + g * 8];
      alo[mr] = *(const short8*)&xl_s[row * BKP + g * 8];
    }
#pragma unroll
    for (int nf = 0; nf < 5; ++nf) {
      int col = wc * 80 + nf * 16 + r;
      bh[nf]  = *(const short8*)&wh_s[col * BKP + g * 8];
      blo[nf] = *(const short8*)&wl_s[col * BKP + g * 8];
    }
#pragma unroll
    for (int mr = 0; mr < 2; ++mr)
#pragma unroll
      for (int nf = 0; nf < 5; ++nf) {
        acc[mr][nf] = __builtin_amdgcn_mfma_f32_16x16x32_bf16(ah[mr],  bh[nf],  acc[mr][nf], 0, 0, 0);
        acc[mr][nf] = __builtin_amdgcn_mfma_f32_16x16x32_bf16(ah[mr],  blo[nf], acc[mr][nf], 0, 0, 0);
        acc[mr][nf] = __builtin_amdgcn_mfma_f32_16x16x32_bf16(alo[mr], bh[nf],  acc[mr][nf], 0, 0, 0);
      }
  }

  // epilogue: C[row=(g*4+q)+16*mr+32*wr][col=r+16*nf+80*wc]
#pragma unroll
  for (int mr = 0; mr < 2; ++mr) {
    int growb = brow + wr * 32 + mr * 16 + g * 4;
#pragma unroll
    for (int nf = 0; nf < 5; ++nf) {
      int gcol = wc * 80 + nf * 16 + r;
#pragma unroll
      for (int q = 0; q < 4; ++q) {
        int grow = growb + q;
        if (grow < M) {
          float v = acc[mr][nf][q];
          if (gcol < HID) xl1[(size_t)grow * HID + gcol] = v;
          else if (gcol < HID + DOUT) ms0[(size_t)grow * DOUT + (gcol - HID)] = v + b0[gcol - HID];
          else if (gcol == HID + DOUT) er1[grow] = v;
        }
      }
    }
  }
}

// ---------- el1 = xl1 @ a1l ----------
__launch_bounds__(256)
__global__ void k_el1(const float* __restrict__ xl1, const float* __restrict__ a1l,
                      float* __restrict__ el1, int M) {
  int wv = threadIdx.x >> 6, lane = threadIdx.x & 63;
  int node = blockIdx.x * 4 + wv;
  if (node >= M) return;
  float2 v = *(const float2*)(xl1 + (size_t)node * HID + lane * 2);
  float2 a = *(const float2*)(a1l + lane * 2);
  float s = fmaf(v.y, a.y, v.x * a.x);
#pragma unroll
  for (int m = 1; m < 64; m <<= 1) s += __shfl_xor(s, m);
  if (lane == 0) el1[node] = s;
}

// ---------- gather layer 1 ----------
__launch_bounds__(256)
__global__ void k_gath1(const int* __restrict__ rowptr, const int* __restrict__ csr_src,
                        const float* __restrict__ el, const float* __restrict__ er,
                        const float* __restrict__ xl1, float* __restrict__ out1, int M) {
  int g = threadIdx.x >> 6, lane = threadIdx.x & 63;
  int d = blockIdx.x * 4 + g;
  if (d >= M) return;
  int lo = rowptr[d], hi = rowptr[d + 1];
  float erd = er[d];
  float a0 = 0.f, a1 = 0.f, wsum = 0.f;
  for (int j = lo; j < hi; ++j) {
    int s = csr_src[j];
    float v = el[s] + erd;
    v = v >= 0.f ? v : 0.2f * v;
    float w = expf(v);
    wsum += w;
    float2 xv = *(const float2*)(xl1 + (size_t)s * HID + lane * 2);
    a0 = fmaf(w, xv.x, a0);
    a1 = fmaf(w, xv.y, a1);
  }
  float inv = 1.f / (wsum + 1e-16f);
  *(float2*)(out1 + (size_t)d * HID + lane * 2) = make_float2(a0 * inv, a1 * inv);
}

// ---------- per-node layer 2 ----------
__launch_bounds__(256)
__global__ void k_node2(const float* __restrict__ out1, const float* __restrict__ b1,
                        const float* __restrict__ W2l, const float* __restrict__ a2l,
                        const float* __restrict__ vr2, float* __restrict__ xl2,
                        float* __restrict__ el2, float* __restrict__ er2, int M) {
  int g = threadIdx.x >> 5, lane = threadIdx.x & 31;
  int node = blockIdx.x * 8 + g;
  if (node >= M) return;
  float4 v = *(const float4*)(out1 + (size_t)node * HID + lane * 4);
  float4 bb = *(const float4*)(b1 + lane * 4);
  float h[4] = {v.x + bb.x, v.y + bb.y, v.z + bb.z, v.w + bb.w};
#pragma unroll
  for (int t = 0; t < 4; ++t) h[t] = h[t] > 0.f ? h[t] : expm1f(h[t]);
  float s[21];
#pragma unroll
  for (int j = 0; j < 21; ++j) {
    const float* wr = (j < 20) ? (W2l + (size_t)j * HID) : vr2;
    float4 wv = *(const float4*)(wr + lane * 4);
    float acc;
    acc = fmaf(h[0], wv.x, 0.f);
    acc = fmaf(h[1], wv.y, acc);
    acc = fmaf(h[2], wv.z, acc);
    acc = fmaf(h[3], wv.w, acc);
#pragma unroll
    for (int m = 1; m < 32; m <<= 1) acc += __shfl_xor(acc, m);
    s[j] = acc;
  }
  if (lane == 0) {
    float el = 0.f;
#pragma unroll
    for (int j = 0; j < 20; ++j) {
      xl2[(size_t)node * DOUT + j] = s[j];
      el = fmaf(s[j], a2l[j], el);
    }
    el2[node] = el;
    er2[node] = s[20];
  }
}

// ---------- gather layer 2 ----------
__launch_bounds__(256)
__global__ void k_gath2(const int* __restrict__ rowptr, const int* __restrict__ csr_src,
                        const float* __restrict__ el, const float* __restrict__ er,
                        const float* __restrict__ xl2, float* __restrict__ out2, int M) {
  int g = threadIdx.x >> 5, lane = threadIdx.x & 31;
  int d = blockIdx.x * 8 + g;
  if (d >= M) return;
  int lo = rowptr[d], hi = rowptr[d + 1];
  float erd = er[d];
  float acc = 0.f, wsum = 0.f;
  for (int j = lo; j < hi; ++j) {
    int s = csr_src[j];
    float v = el[s] + erd;
    v = v >= 0.f ? v : 0.2f * v;
    float w = expf(v);
    wsum += w;
    if (lane < DOUT) acc = fmaf(w, xl2[(size_t)s * DOUT + lane], acc);
  }
  if (lane < DOUT) out2[(size_t)d * DOUT + lane] = acc / (wsum + 1e-16f);
}

// ---------- column sum of exp(ms0) ----------
__launch_bounds__(256)
__global__ void k_colsum1(const float* __restrict__ ms0, float* __restrict__ partial, int M) {
  __shared__ float lds[4][20];
  float sm[20];
#pragma unroll
  for (int j = 0; j < 20; ++j) sm[j] = 0.f;
  int stride = gridDim.x * blockDim.x;
  for (int i = blockIdx.x * blockDim.x + threadIdx.x; i < M; i += stride) {
    const float4* row = (const float4*)(ms0 + (size_t)i * DOUT);
#pragma unroll
    for (int q = 0; q < 5; ++q) {
      float4 v = row[q];
      sm[q * 4 + 0] += expf(v.x);
      sm[q * 4 + 1] += expf(v.y);
      sm[q * 4 + 2] += expf(v.z);
      sm[q * 4 + 3] += expf(v.w);
    }
  }
#pragma unroll
  for (int j = 0; j < 20; ++j) {
#pragma unroll
    for (int k = 1; k < 64; k <<= 1) sm[j] += __shfl_xor(sm[j], k);
  }
  int wave = threadIdx.x >> 6, lane = threadIdx.x & 63;
  if (lane == 0) {
#pragma unroll
    for (int j = 0; j < 20; ++j) lds[wave][j] = sm[j];
  }
  __syncthreads();
  if (threadIdx.x < 20)
    partial[blockIdx.x * 20 + threadIdx.x] =
        lds[0][threadIdx.x] + lds[1][threadIdx.x] + lds[2][threadIdx.x] + lds[3][threadIdx.x];
}

__global__ void k_colsum2(const float* __restrict__ partial, float* __restrict__ colsum) {
  int j = threadIdx.x;
  if (j < 20) {
    float s = 0.f;
    for (int b = 0; b < NBLK_COL; ++b) s += partial[b * 20 + j];
    colsum[j] = s;
  }
}

// ---------- final ----------
__launch_bounds__(256)
__global__ void k_final(const float* __restrict__ ms0, const float* __restrict__ out2,
                        const float* __restrict__ b2, const float* __restrict__ colsum,
                        float* __restrict__ out, int M) {
  int i = blockIdx.x * 256 + threadIdx.x;
  if (i >= M) return;
  float ms1[20];
  const float4* r2 = (const float4*)(out2 + (size_t)i * DOUT);
#pragma unroll
  for (int q = 0; q < 5; ++q) {
    float4 v = r2[q];
    ms1[q * 4 + 0] = v.x + b2[q * 4 + 0];
    ms1[q * 4 + 1] = v.y + b2[q * 4 + 1];
    ms1[q * 4 + 2] = v.z + b2[q * 4 + 2];
    ms1[q * 4 + 3] = v.w + b2[q * 4 + 3];
  }
  float rmax = -INFINITY;
#pragma unroll
  for (int j = 0; j < 20; ++j) rmax = fmaxf(rmax, ms1[j]);
  float rsum = 0.f;
#pragma unroll
  for (int j = 0; j < 20; ++j) { ms1[j] = expf(ms1[j] - rmax); rsum += ms1[j]; }
  const float4* r0 = (const float4*)(ms0 + (size_t)i * DOUT);
  float o[20];
#pragma unroll
  for (int q = 0; q < 5; ++q) {
    float4 v = r0[q];
    o[q * 4 + 0] = expf(v.x) / colsum[q * 4 + 0] * (ms1[q * 4 + 0] / rsum);
    o[q * 4 + 1] = expf(v.y) / colsum[q * 4 + 1] * (ms1[q * 4 + 1] / rsum);
    o[q * 4 + 2] = expf(v.z) / colsum[q * 4 + 2] * (ms1[q * 4 + 2] / rsum);
    o[q * 4 + 3] = expf(v.w) / colsum[q * 4 + 3] * (ms1[q * 4 + 3] / rsum);
  }
  float4* po = (float4*)(out + (size_t)i * DOUT);
#pragma unroll
  for (int q = 0; q < 5; ++q)
    po[q] = make_float4(o[q * 4 + 0], o[q * 4 + 1], o[q * 4 + 2], o[q * 4 + 3]);
}

extern "C" void kernel_launch(void* const* d_in, const int* in_sizes, int n_in,
                              void* d_out, int out_size, void* d_ws, size_t ws_size,
                              hipStream_t stream) {
  const float* x   = (const float*)d_in[0];
  const int*   ei  = (const int*)d_in[1];
  const float* W0  = (const float*)d_in[2];
  const float* b0  = (const float*)d_in[3];
  const float* W1l = (const float*)d_in[4];
  const float* W1r = (const float*)d_in[5];
  const float* a1l = (const float*)d_in[6];
  const float* a1r = (const float*)d_in[7];
  const float* b1  = (const float*)d_in[8];
  const float* W2l = (const float*)d_in[9];
  const float* W2r = (const float*)d_in[10];
  const float* a2l = (const float*)d_in[11];
  const float* a2r = (const float*)d_in[12];
  const float* b2  = (const float*)d_in[13];
  const int M = in_sizes[0] / DIN;   // 50000
  const int E = in_sizes[1] / 2;     // 500000
  const int NB_SCAN = (M + SCAN_TILE - 1) / SCAN_TILE;   // 49 (<=64 required)
  (void)n_in; (void)out_size; (void)ws_size;

  char* w = (char*)d_ws;
  size_t off = 0;
  auto alloc = [&](size_t bytes) -> void* {
    void* p = w + off;
    off += (bytes + 255) & ~(size_t)255;
    return p;
  };
  float* xl1     = (float*)alloc((size_t)M * HID * 4);
  float* el1     = (float*)alloc((size_t)M * 4);
  float* er1     = (float*)alloc((size_t)M * 4);
  float* ms0     = (float*)alloc((size_t)M * DOUT * 4);
  float* out1    = (float*)alloc((size_t)M * HID * 4);
  float* xl2     = (float*)alloc((size_t)M * DOUT * 4);
  float* el2     = (float*)alloc((size_t)M * 4);
  float* er2     = (float*)alloc((size_t)M * 4);
  float* out2    = (float*)alloc((size_t)M * DOUT * 4);
  float* partial = (float*)alloc((size_t)NBLK_COL * 20 * 4);
  float* colsum  = (float*)alloc(32 * 4);
  float* vr1     = (float*)alloc(DIN * 4);
  float* vr2     = (float*)alloc(HID * 4);
  u16*   whcat   = (u16*)alloc((size_t)NCAT * DIN * 2);
  u16*   wlcat   = (u16*)alloc((size_t)NCAT * DIN * 2);
  int*   deg     = (int*)alloc((size_t)M * 4);
  int*   rowptr  = (int*)alloc((size_t)(M + 1) * 4);
  int*   cursor  = (int*)alloc((size_t)M * 4);
  int*   csr_src = (int*)alloc((size_t)E * 4);
  int*   tilesum = (int*)alloc(64 * 4);
  int*   tileoff = (int*)alloc(64 * 4);

  hipMemsetAsync(deg, 0, (size_t)M * 4, stream);

  k_prep<<<1, 256, 0, stream>>>(W1r, a1r, W2r, a2r, vr1, vr2);
  k_prepw<<<(NCAT * DIN + 255) / 256, 256, 0, stream>>>(W1l, W0, vr1, whcat, wlcat);
  k_hist<<<1024, 256, 0, stream>>>(ei, deg, E);
  k_scan1<<<NB_SCAN, 256, 0, stream>>>(deg, tilesum, M);
  k_scan2<<<1, 64, 0, stream>>>(tilesum, tileoff, rowptr, NB_SCAN, M);
  k_scan3<<<NB_SCAN, 256, 0, stream>>>(deg, tileoff, rowptr, cursor, M);
  k_csr<<<1024, 256, 0, stream>>>(ei, cursor, csr_src, E);

  k_fused1<<<(M + 63) / 64, 256, 0, stream>>>(x, whcat, wlcat, b0, xl1, ms0, er1, M);
  k_el1<<<(M + 3) / 4, 256, 0, stream>>>(xl1, a1l, el1, M);

  k_gath1<<<(M + 3) / 4, 256, 0, stream>>>(rowptr, csr_src, el1, er1, xl1, out1, M);
  k_node2<<<(M + 7) / 8, 256, 0, stream>>>(out1, b1, W2l, a2l, vr2, xl2, el2, er2, M);
  k_gath2<<<(M + 7) / 8, 256, 0, stream>>>(rowptr, csr_src, el2, er2, xl2, out2, M);

  k_colsum1<<<NBLK_COL, 256, 0, stream>>>(ms0, partial, M);
  k_colsum2<<<1, 64, 0, stream>>>(partial, colsum);
  k_final<<<(M + 255) / 256, 256, 0, stream>>>(ms0, out2, b2, colsum, (float*)d_out, M);
}